// Round 1
// baseline (566.384 us; speedup 1.0000x reference)
//
#include <hip/hip_runtime.h>
#include <hip/hip_bf16.h>

#define B_ 4
#define S_ 2048
#define D_ 1024
#define H_ 16
#define DK_ 64
#define M_ (B_*S_)   // 8192

typedef unsigned short ushort_t;
typedef __bf16 bf16x8 __attribute__((ext_vector_type(8)));
typedef float f32x4 __attribute__((ext_vector_type(4)));

__device__ __forceinline__ ushort_t f2bf(float f) {
  union { float f; unsigned u; } v; v.f = f;
  unsigned u = v.u;
  return (ushort_t)((u + 0x7fffu + ((u >> 16) & 1u)) >> 16);
}

__device__ __forceinline__ void gload16(const void* g, void* l) {
  __builtin_amdgcn_global_load_lds(
      (const __attribute__((address_space(1))) unsigned int*)g,
      (__attribute__((address_space(3))) unsigned int*)l, 16, 0, 0);
}

// ---------------- convert q,k,v f32 -> bf16 ----------------
__global__ void k_convert(const float* __restrict__ q, const float* __restrict__ k,
                          const float* __restrict__ v, ushort_t* __restrict__ out) {
  const int n4 = (M_*D_) / 4;  // 2^21 per array
  int tid = blockIdx.x * blockDim.x + threadIdx.x;
  int stride = gridDim.x * blockDim.x;
  for (int i = tid; i < 3 * n4; i += stride) {
    int a = i >> 21;
    int r = i & (n4 - 1);
    const float4* src = (const float4*)(a == 0 ? q : (a == 1 ? k : v));
    float4 x = src[r];
    ushort4 o;
    o.x = f2bf(x.x); o.y = f2bf(x.y); o.z = f2bf(x.z); o.w = f2bf(x.w);
    *(ushort4*)(out + (size_t)a * (M_*D_) + (size_t)r * 4) = o;
  }
}

// ---------------- weight transpose+convert: Wt[n][k] = bf16(W[k][n]) ----------------
__global__ void k_wtrans(const float* __restrict__ Wq, const float* __restrict__ Wk,
                         const float* __restrict__ Wv, const float* __restrict__ Wo,
                         ushort_t* __restrict__ wt) {
  __shared__ ushort_t ls[64][72];
  int bid = blockIdx.x;
  int w = bid >> 8;
  int tile = bid & 255;
  int tk = (tile >> 4) * 64;
  int tn = (tile & 15) * 64;
  const float* W = (w == 0 ? Wq : w == 1 ? Wk : w == 2 ? Wv : Wo);
  int t = threadIdx.x;
  int r = t >> 4;
  int c = (t & 15) * 4;
#pragma unroll
  for (int i = 0; i < 4; i++) {
    int rr = r + i * 16;
    float4 x = *(const float4*)(W + (size_t)(tk + rr) * D_ + tn + c);
    ls[rr][c] = f2bf(x.x); ls[rr][c+1] = f2bf(x.y);
    ls[rr][c+2] = f2bf(x.z); ls[rr][c+3] = f2bf(x.w);
  }
  __syncthreads();
  ushort_t* dst = wt + (size_t)w * D_ * D_;
#pragma unroll
  for (int i = 0; i < 4; i++) {
    int rr = r + i * 16;
    ushort4 o;
    o.x = ls[c+0][rr]; o.y = ls[c+1][rr]; o.z = ls[c+2][rr]; o.w = ls[c+3][rr];
    *(ushort4*)(dst + (size_t)(tn + rr) * D_ + tk + c) = o;
  }
}

// ---------------- GEMM: C[M,1024] = A[M,1024] @ Bt[1024,1024]^T + bias ----------------
// EPI 0: bf16 out to [B,H,S,DK];  EPI 1: f32 out row-major [M,1024]
template<int EPI>
__global__ __launch_bounds__(256, 2) void k_gemm(
    const ushort_t* __restrict__ A, const ushort_t* __restrict__ Bt,
    const float* __restrict__ bias, void* __restrict__ out) {
  __shared__ ushort_t As[128 * 32];
  __shared__ ushort_t Bs[128 * 32];
  const int K = D_;
  int nwg = gridDim.x;           // 512, divisible by 8
  int cpx = nwg >> 3;
  int bid = blockIdx.x;
  int wg = (bid & 7) * cpx + (bid >> 3);   // XCD-aware swizzle (bijective)
  int by = wg >> 3;
  int bx = wg & 7;
  int m0 = by * 128, n0 = bx * 128;
  int t = threadIdx.x;
  int l = t & 63, wid = t >> 6;
  int wy = wid >> 1, wx = wid & 1;
  int lr = l & 15, lg = l >> 4;

  f32x4 acc[4][4] = {};
  const ushort_t* ga0 = A  + (size_t)(m0 + (t >> 2)) * K + (t & 3) * 8;
  const ushort_t* gb0 = Bt + (size_t)(n0 + (t >> 2)) * K + (t & 3) * 8;
  ushort_t* lA = As + wid * 512;   // wave-uniform LDS base; HW adds lane*16B
  ushort_t* lB = Bs + wid * 512;

  for (int k0 = 0; k0 < K; k0 += 32) {
    gload16(ga0 + k0, lA);
    gload16(ga0 + (size_t)64 * K + k0, lA + 2048);
    gload16(gb0 + k0, lB);
    gload16(gb0 + (size_t)64 * K + k0, lB + 2048);
    __syncthreads();   // drains vmcnt before barrier
    bf16x8 a[4], b[4];
#pragma unroll
    for (int mi = 0; mi < 4; mi++)
      a[mi] = *(const bf16x8*)(As + (wy * 64 + mi * 16 + lr) * 32 + lg * 8);
#pragma unroll
    for (int ni = 0; ni < 4; ni++)
      b[ni] = *(const bf16x8*)(Bs + (wx * 64 + ni * 16 + lr) * 32 + lg * 8);
#pragma unroll
    for (int mi = 0; mi < 4; mi++)
#pragma unroll
      for (int ni = 0; ni < 4; ni++)
        acc[mi][ni] = __builtin_amdgcn_mfma_f32_16x16x32_bf16(a[mi], b[ni], acc[mi][ni], 0, 0, 0);
    __syncthreads();
  }
#pragma unroll
  for (int mi = 0; mi < 4; mi++)
#pragma unroll
    for (int ni = 0; ni < 4; ni++) {
      int col = n0 + wx * 64 + ni * 16 + lr;
      float bs = bias[col];
#pragma unroll
      for (int j = 0; j < 4; j++) {
        int row = m0 + wy * 64 + mi * 16 + lg * 4 + j;
        float val = acc[mi][ni][j] + bs;
        if (EPI == 0) {
          int bi = row >> 11, s = row & 2047;
          int h = col >> 6, d = col & 63;
          ((ushort_t*)out)[(((size_t)bi * H_ + h) * S_ + s) * DK_ + d] = f2bf(val);
        } else {
          ((float*)out)[(size_t)row * D_ + col] = val;
        }
      }
    }
}

// ---------------- V transpose per (b,h): Vt[d][s] = Vp[s][d] ----------------
__global__ void k_vtrans(const ushort_t* __restrict__ Vp, ushort_t* __restrict__ Vt) {
  __shared__ ushort_t ls[64][72];
  int bid = blockIdx.x;
  int bh = bid >> 5;
  int t0 = (bid & 31) * 64;
  int t = threadIdx.x;
  const ushort_t* src = Vp + (size_t)bh * S_ * DK_;
#pragma unroll
  for (int i = 0; i < 2; i++) {
    int r = i * 32 + (t >> 3);
    int c = (t & 7) * 8;
    *(float4*)&ls[r][c] = *(const float4*)(src + (size_t)(t0 + r) * DK_ + c);
  }
  __syncthreads();
  ushort_t* dst = Vt + (size_t)bh * DK_ * S_;
#pragma unroll
  for (int i = 0; i < 2; i++) {
    int d = i * 32 + (t >> 3);
    int c = (t & 7) * 8;
    union { ushort_t u[8]; float4 v; } tmp;
#pragma unroll
    for (int j = 0; j < 8; j++) tmp.u[j] = ls[c + j][d];
    *(float4*)(dst + (size_t)d * S_ + t0 + c) = tmp.v;
  }
}

// ---------------- flash attention ----------------
// grid: 64 bh * 16 q-tiles(128). 4 waves x 32 q-rows. KVBLK=64.
__global__ __launch_bounds__(256, 2) void k_attn(
    const ushort_t* __restrict__ Qp, const ushort_t* __restrict__ Kp,
    const ushort_t* __restrict__ Vt, ushort_t* __restrict__ ctx) {
  __shared__ ushort_t Ks[64 * 64];   // [kv][dk], XOR-swizzled 16B chunks
  __shared__ ushort_t Vs[64 * 64];   // [d][t],  XOR-swizzled
  __shared__ ushort_t Ps[128 * 64];  // [q][t],  XOR-swizzled
  int bid = blockIdx.x;
  int bh = bid >> 4;
  int qt = bid & 15;
  int t = threadIdx.x;
  int l = t & 63, wid = t >> 6;
  int lr = l & 15, lg = l >> 4;
  const float csc = 0.125f * 1.44269504f;  // scale * log2(e)

  const ushort_t* Qb = Qp + (size_t)bh * S_ * DK_;
  const ushort_t* Kb = Kp + (size_t)bh * S_ * DK_;
  const ushort_t* Vb = Vt + (size_t)bh * DK_ * S_;

  bf16x8 qf[2][2];
  int q0 = qt * 128 + wid * 32;
#pragma unroll
  for (int rt = 0; rt < 2; rt++)
#pragma unroll
    for (int kc = 0; kc < 2; kc++)
      qf[rt][kc] = *(const bf16x8*)(Qb + (size_t)(q0 + rt * 16 + lr) * DK_ + kc * 32 + lg * 8);

  f32x4 o[2][4] = {};
  float mrow[2][4], lrow[2][4];
#pragma unroll
  for (int rt = 0; rt < 2; rt++)
#pragma unroll
    for (int j = 0; j < 4; j++) { mrow[rt][j] = -1e30f; lrow[rt][j] = 0.f; }

  int sr = t >> 3;       // 0..31 (row within a 32-row half-tile)
  int cs = t & 7;        // 16B slot within 128B row
  ushort_t* lK = Ks + wid * 512;
  ushort_t* lV = Vs + wid * 512;

  for (int t0 = 0; t0 < S_; t0 += 64) {
    // stage K,V; LDS dest is linear, global source pre-swizzled (slot cs holds chunk cs^(row&7))
    int r1 = 32 + sr;
    gload16(Kb + (size_t)(t0 + sr) * DK_ + (cs ^ (sr & 7)) * 8, lK);
    gload16(Kb + (size_t)(t0 + r1) * DK_ + (cs ^ (r1 & 7)) * 8, lK + 2048);
    gload16(Vb + (size_t)sr * S_ + t0 + (cs ^ (sr & 7)) * 8, lV);
    gload16(Vb + (size_t)r1 * S_ + t0 + (cs ^ (r1 & 7)) * 8, lV + 2048);
    __syncthreads();

    // S = Q @ K^T
    f32x4 s[2][4] = {};
#pragma unroll
    for (int kc = 0; kc < 2; kc++) {
#pragma unroll
      for (int ct = 0; ct < 4; ct++) {
        int r = ct * 16 + lr;
        bf16x8 b = *(const bf16x8*)(Ks + r * 64 + (((kc * 4 + lg) ^ (r & 7)) * 8));
#pragma unroll
        for (int rt = 0; rt < 2; rt++)
          s[rt][ct] = __builtin_amdgcn_mfma_f32_16x16x32_bf16(qf[rt][kc], b, s[rt][ct], 0, 0, 0);
      }
    }

    // online softmax (base-2 domain, scale folded in)
    float al[2][4];
#pragma unroll
    for (int rt = 0; rt < 2; rt++)
#pragma unroll
      for (int ct = 0; ct < 4; ct++) s[rt][ct] *= csc;
#pragma unroll
    for (int rt = 0; rt < 2; rt++) {
#pragma unroll
      for (int j = 0; j < 4; j++) {
        float rm = fmaxf(fmaxf(s[rt][0][j], s[rt][1][j]), fmaxf(s[rt][2][j], s[rt][3][j]));
        rm = fmaxf(rm, __shfl_xor(rm, 1));
        rm = fmaxf(rm, __shfl_xor(rm, 2));
        rm = fmaxf(rm, __shfl_xor(rm, 4));
        rm = fmaxf(rm, __shfl_xor(rm, 8));
        float mn = fmaxf(mrow[rt][j], rm);
        float a = exp2f(mrow[rt][j] - mn);
        mrow[rt][j] = mn;
        al[rt][j] = a;
        float rs = 0.f;
        int q = wid * 32 + rt * 16 + lg * 4 + j;
#pragma unroll
        for (int ct = 0; ct < 4; ct++) {
          float p = exp2f(s[rt][ct][j] - mn);
          rs += p;
          int tl = ct * 16 + lr;
          int chunk = tl >> 3;
          int byteoff = q * 128 + ((chunk ^ (q & 7)) * 16) + (tl & 7) * 2;
          *(ushort_t*)((char*)Ps + byteoff) = f2bf(p);
        }
        rs += __shfl_xor(rs, 1);
        rs += __shfl_xor(rs, 2);
        rs += __shfl_xor(rs, 4);
        rs += __shfl_xor(rs, 8);
        lrow[rt][j] = lrow[rt][j] * a + rs;
      }
    }
#pragma unroll
    for (int rt = 0; rt < 2; rt++)
#pragma unroll
      for (int dt = 0; dt < 4; dt++)
#pragma unroll
        for (int j = 0; j < 4; j++) o[rt][dt][j] *= al[rt][j];
    __syncthreads();

    // O += P @ V
#pragma unroll
    for (int kc = 0; kc < 2; kc++) {
      bf16x8 a[2];
#pragma unroll
      for (int rt = 0; rt < 2; rt++) {
        int q = wid * 32 + rt * 16 + lr;
        a[rt] = *(const bf16x8*)((char*)Ps + q * 128 + (((kc * 4 + lg) ^ (q & 7)) * 16));
      }
#pragma unroll
      for (int dt = 0; dt < 4; dt++) {
        int d = dt * 16 + lr;
        bf16x8 b = *(const bf16x8*)(Vs + d * 64 + (((kc * 4 + lg) ^ (d & 7)) * 8));
#pragma unroll
        for (int rt = 0; rt < 2; rt++)
          o[rt][dt] = __builtin_amdgcn_mfma_f32_16x16x32_bf16(a[rt], b, o[rt][dt], 0, 0, 0);
      }
    }
    __syncthreads();
  }

  // epilogue: ctx[b][s][h][d] bf16
  int bb = bh >> 4, h = bh & 15;
#pragma unroll
  for (int rt = 0; rt < 2; rt++)
#pragma unroll
    for (int j = 0; j < 4; j++) {
      int srow = qt * 128 + wid * 32 + rt * 16 + lg * 4 + j;
      float inv = 1.f / lrow[rt][j];
#pragma unroll
      for (int dt = 0; dt < 4; dt++) {
        int d = dt * 16 + lr;
        ctx[(((size_t)bb * S_ + srow) * H_ + h) * DK_ + d] = f2bf(o[rt][dt][j] * inv);
      }
    }
}

extern "C" void kernel_launch(void* const* d_in, const int* in_sizes, int n_in,
                              void* d_out, int out_size, void* d_ws, size_t ws_size,
                              hipStream_t stream) {
  const float* query = (const float*)d_in[0];
  const float* key   = (const float*)d_in[1];
  const float* value = (const float*)d_in[2];
  const float* Wq = (const float*)d_in[4];
  const float* bq = (const float*)d_in[5];
  const float* Wk = (const float*)d_in[6];
  const float* bk = (const float*)d_in[7];
  const float* Wv = (const float*)d_in[8];
  const float* bv = (const float*)d_in[9];
  const float* Wo = (const float*)d_in[10];
  const float* bo = (const float*)d_in[11];

  char* ws = (char*)d_ws;
  const size_t MD = (size_t)M_ * D_;      // 8388608 elements
  const size_t DD = (size_t)D_ * D_;
  ushort_t* xb  = (ushort_t*)ws;                              // [3][M][D] bf16 inputs
  ushort_t* wt  = (ushort_t*)(ws + 3 * MD * 2);               // [4][D][D] bf16 W^T
  ushort_t* Qp  = (ushort_t*)(ws + 3 * MD * 2 + 4 * DD * 2);  // [B,H,S,DK]
  ushort_t* Kp  = Qp + MD;
  ushort_t* Vp  = Kp + MD;
  ushort_t* Vt  = xb + MD;   // reuse xb[1] (key copy dead after K-proj)
  ushort_t* ctx = xb;        // reuse xb[0] (query copy dead after Q-proj)

  k_convert<<<2048, 256, 0, stream>>>(query, key, value, xb);
  k_wtrans<<<1024, 256, 0, stream>>>(Wq, Wk, Wv, Wo, wt);
  k_gemm<0><<<512, 256, 0, stream>>>(xb,          wt,          bq, Qp);
  k_gemm<0><<<512, 256, 0, stream>>>(xb + MD,     wt + DD,     bk, Kp);
  k_gemm<0><<<512, 256, 0, stream>>>(xb + 2 * MD, wt + 2 * DD, bv, Vp);
  k_vtrans<<<2048, 256, 0, stream>>>(Vp, Vt);
  k_attn<<<1024, 256, 0, stream>>>(Qp, Kp, Vt, ctx);
  k_gemm<1><<<512, 256, 0, stream>>>(ctx, wt + 3 * DD, bo, (float*)d_out);
}

// Round 3
// 537.937 us; speedup vs baseline: 1.0529x; 1.0529x over previous
//
#include <hip/hip_runtime.h>
#include <hip/hip_bf16.h>

#define B_ 4
#define S_ 2048
#define D_ 1024
#define H_ 16
#define DK_ 64
#define M_ (B_*S_)   // 8192

typedef unsigned short ushort_t;
typedef __bf16 bf16x8 __attribute__((ext_vector_type(8)));
typedef float f32x4 __attribute__((ext_vector_type(4)));
typedef float f32x16 __attribute__((ext_vector_type(16)));
typedef unsigned uint2v __attribute__((ext_vector_type(2)));

__device__ __forceinline__ ushort_t f2bf(float f) {
  union { float f; unsigned u; } v; v.f = f;
  unsigned u = v.u;
  return (ushort_t)((u + 0x7fffu + ((u >> 16) & 1u)) >> 16);
}

__device__ __forceinline__ void gload16(const void* g, void* l) {
  __builtin_amdgcn_global_load_lds(
      (const __attribute__((address_space(1))) unsigned int*)g,
      (__attribute__((address_space(3))) unsigned int*)l, 16, 0, 0);
}

// swap(a.lane[i+32], b.lane[i]) — gfx950 v_permlane32_swap_b32
__device__ __forceinline__ void plane32_swap(unsigned& a, unsigned& b) {
#if __has_builtin(__builtin_amdgcn_permlane32_swap)
  uint2v r = __builtin_amdgcn_permlane32_swap(a, b, false, false);
  a = r.x; b = r.y;
#else
  unsigned pa = __shfl_xor((int)a, 32), pb = __shfl_xor((int)b, 32);
  bool hi = (threadIdx.x & 32) != 0;
  unsigned na = hi ? pb : a;
  unsigned nb = hi ? b : pa;
  a = na; b = nb;
#endif
}

// ---------------- convert q,k,v f32 -> bf16 ----------------
__global__ void k_convert(const float* __restrict__ q, const float* __restrict__ k,
                          const float* __restrict__ v, ushort_t* __restrict__ out) {
  const int n4 = (M_*D_) / 4;  // 2^21 per array
  int tid = blockIdx.x * blockDim.x + threadIdx.x;
  int stride = gridDim.x * blockDim.x;
  for (int i = tid; i < 3 * n4; i += stride) {
    int a = i >> 21;
    int r = i & (n4 - 1);
    const float4* src = (const float4*)(a == 0 ? q : (a == 1 ? k : v));
    float4 x = src[r];
    ushort4 o;
    o.x = f2bf(x.x); o.y = f2bf(x.y); o.z = f2bf(x.z); o.w = f2bf(x.w);
    *(ushort4*)(out + (size_t)a * (M_*D_) + (size_t)r * 4) = o;
  }
}

// ---------------- weight transpose+convert: Wt[n][k] = bf16(W[k][n]) ----------------
__global__ void k_wtrans(const float* __restrict__ Wq, const float* __restrict__ Wk,
                         const float* __restrict__ Wv, const float* __restrict__ Wo,
                         ushort_t* __restrict__ wt) {
  __shared__ ushort_t ls[64][72];
  int bid = blockIdx.x;
  int w = bid >> 8;
  int tile = bid & 255;
  int tk = (tile >> 4) * 64;
  int tn = (tile & 15) * 64;
  const float* W = (w == 0 ? Wq : w == 1 ? Wk : w == 2 ? Wv : Wo);
  int t = threadIdx.x;
  int r = t >> 4;
  int c = (t & 15) * 4;
#pragma unroll
  for (int i = 0; i < 4; i++) {
    int rr = r + i * 16;
    float4 x = *(const float4*)(W + (size_t)(tk + rr) * D_ + tn + c);
    ls[rr][c] = f2bf(x.x); ls[rr][c+1] = f2bf(x.y);
    ls[rr][c+2] = f2bf(x.z); ls[rr][c+3] = f2bf(x.w);
  }
  __syncthreads();
  ushort_t* dst = wt + (size_t)w * D_ * D_;
#pragma unroll
  for (int i = 0; i < 4; i++) {
    int rr = r + i * 16;
    ushort4 o;
    o.x = ls[c+0][rr]; o.y = ls[c+1][rr]; o.z = ls[c+2][rr]; o.w = ls[c+3][rr];
    *(ushort4*)(dst + (size_t)(tn + rr) * D_ + tk + c) = o;
  }
}

// ---------------- GEMM: C[M,1024] = A[M,1024] @ Bt[1024,1024]^T + bias ----------------
// EPI 0: bf16 out to [B,H,S,DK];  EPI 1: f32 out row-major [M,1024]
template<int EPI>
__global__ __launch_bounds__(256, 2) void k_gemm(
    const ushort_t* __restrict__ A, const ushort_t* __restrict__ Bt,
    const float* __restrict__ bias, void* __restrict__ out) {
  __shared__ ushort_t As[128 * 32];
  __shared__ ushort_t Bs[128 * 32];
  const int K = D_;
  int nwg = gridDim.x;           // 512, divisible by 8
  int cpx = nwg >> 3;
  int bid = blockIdx.x;
  int wg = (bid & 7) * cpx + (bid >> 3);   // XCD-aware swizzle (bijective)
  int by = wg >> 3;
  int bx = wg & 7;
  int m0 = by * 128, n0 = bx * 128;
  int t = threadIdx.x;
  int l = t & 63, wid = t >> 6;
  int wy = wid >> 1, wx = wid & 1;
  int lr = l & 15, lg = l >> 4;

  f32x4 acc[4][4] = {};
  const ushort_t* ga0 = A  + (size_t)(m0 + (t >> 2)) * K + (t & 3) * 8;
  const ushort_t* gb0 = Bt + (size_t)(n0 + (t >> 2)) * K + (t & 3) * 8;
  ushort_t* lA = As + wid * 512;   // wave-uniform LDS base; HW adds lane*16B
  ushort_t* lB = Bs + wid * 512;

  for (int k0 = 0; k0 < K; k0 += 32) {
    gload16(ga0 + k0, lA);
    gload16(ga0 + (size_t)64 * K + k0, lA + 2048);
    gload16(gb0 + k0, lB);
    gload16(gb0 + (size_t)64 * K + k0, lB + 2048);
    __syncthreads();   // drains vmcnt before barrier
    bf16x8 a[4], b[4];
#pragma unroll
    for (int mi = 0; mi < 4; mi++)
      a[mi] = *(const bf16x8*)(As + (wy * 64 + mi * 16 + lr) * 32 + lg * 8);
#pragma unroll
    for (int ni = 0; ni < 4; ni++)
      b[ni] = *(const bf16x8*)(Bs + (wx * 64 + ni * 16 + lr) * 32 + lg * 8);
#pragma unroll
    for (int mi = 0; mi < 4; mi++)
#pragma unroll
      for (int ni = 0; ni < 4; ni++)
        acc[mi][ni] = __builtin_amdgcn_mfma_f32_16x16x32_bf16(a[mi], b[ni], acc[mi][ni], 0, 0, 0);
    __syncthreads();
  }
#pragma unroll
  for (int mi = 0; mi < 4; mi++)
#pragma unroll
    for (int ni = 0; ni < 4; ni++) {
      int col = n0 + wx * 64 + ni * 16 + lr;
      float bs = bias[col];
#pragma unroll
      for (int j = 0; j < 4; j++) {
        int row = m0 + wy * 64 + mi * 16 + lg * 4 + j;
        float val = acc[mi][ni][j] + bs;
        if (EPI == 0) {
          int bi = row >> 11, s = row & 2047;
          int h = col >> 6, d = col & 63;
          ((ushort_t*)out)[(((size_t)bi * H_ + h) * S_ + s) * DK_ + d] = f2bf(val);
        } else {
          ((float*)out)[(size_t)row * D_ + col] = val;
        }
      }
    }
}

// ---------------- V transpose per (b,h): Vt[d][s] = Vp[s][d] ----------------
__global__ void k_vtrans(const ushort_t* __restrict__ Vp, ushort_t* __restrict__ Vt) {
  __shared__ ushort_t ls[64][72];
  int bid = blockIdx.x;
  int bh = bid >> 5;
  int t0 = (bid & 31) * 64;
  int t = threadIdx.x;
  const ushort_t* src = Vp + (size_t)bh * S_ * DK_;
#pragma unroll
  for (int i = 0; i < 2; i++) {
    int r = i * 32 + (t >> 3);
    int c = (t & 7) * 8;
    *(float4*)&ls[r][c] = *(const float4*)(src + (size_t)(t0 + r) * DK_ + c);
  }
  __syncthreads();
  ushort_t* dst = Vt + (size_t)bh * DK_ * S_;
#pragma unroll
  for (int i = 0; i < 2; i++) {
    int d = i * 32 + (t >> 3);
    int c = (t & 7) * 8;
    union { ushort_t u[8]; float4 v; } tmp;
#pragma unroll
    for (int j = 0; j < 8; j++) tmp.u[j] = ls[c + j][d];
    *(float4*)(dst + (size_t)d * S_ + t0 + c) = tmp.v;
  }
}

// ---------------- flash attention: swapped-operand 32x32, no LDS, no barriers ----
// grid: 1024 blocks; bid = qt*64 + bh  (=> xcd = bh%8, groups one bh-set per XCD L2)
// 4 waves/block, each wave owns 32 q rows. KVBLK=64, K/V read direct from L1/L2.
__global__ __launch_bounds__(256, 2) void k_attn(
    const ushort_t* __restrict__ Qp, const ushort_t* __restrict__ Kp,
    const ushort_t* __restrict__ Vt, ushort_t* __restrict__ ctx) {
  int bid = blockIdx.x;
  int bh = bid & 63;
  int qt = bid >> 6;
  int t = threadIdx.x;
  int l = t & 63, wid = t >> 6;
  int l31 = l & 31, hi = l >> 5;
  const float csc = 0.125f * 1.44269504f;  // scale * log2(e)

  const ushort_t* Qb = Qp + (size_t)bh * S_ * DK_;
  const ushort_t* Kb = Kp + (size_t)bh * S_ * DK_;
  const ushort_t* Vb = Vt + (size_t)bh * DK_ * S_;

  int q0 = qt * 128 + wid * 32;
  // Q as B-fragments (col q = l31, k-rows dk = ks*16 + hi*8 + j)
  bf16x8 qf[4];
  const ushort_t* qp = Qb + (size_t)(q0 + l31) * DK_ + hi * 8;
#pragma unroll
  for (int ks = 0; ks < 4; ks++) qf[ks] = *(const bf16x8*)(qp + ks * 16);

  const ushort_t* kp = Kb + (size_t)l31 * DK_ + hi * 8;   // A-frag base: row kv=l31
  const ushort_t* vp = Vb + (size_t)l31 * S_ + hi * 8;    // A-frag base: row d=l31

  f32x16 o0 = {}, o1 = {};
  float m = -1e30f, lsum = 0.f;

  for (int t0 = 0; t0 < S_; t0 += 64) {
    // direct-from-global fragment loads (L1/L2-resident; no staging, no barriers)
    bf16x8 kf0[4], kf1[4], vf0[4], vf1[4];
#pragma unroll
    for (int ks = 0; ks < 4; ks++) {
      kf0[ks] = *(const bf16x8*)(kp + ks * 16);
      kf1[ks] = *(const bf16x8*)(kp + 32 * DK_ + ks * 16);
      vf0[ks] = *(const bf16x8*)(vp + ks * 16);
      vf1[ks] = *(const bf16x8*)(vp + (size_t)32 * S_ + ks * 16);
    }

    // S^T[kv][q] = K[kv][dk] * Q^T[dk][q]
    f32x16 s0 = {}, s1 = {};
#pragma unroll
    for (int ks = 0; ks < 4; ks++) {
      s0 = __builtin_amdgcn_mfma_f32_32x32x16_bf16(kf0[ks], qf[ks], s0, 0, 0, 0);
      s1 = __builtin_amdgcn_mfma_f32_32x32x16_bf16(kf1[ks], qf[ks], s1, 0, 0, 0);
    }

    // row max (lane owns q = l31; partner lane l^32 has the other kv rows)
    float pmax = s0[0];
#pragma unroll
    for (int r = 1; r < 16; r++) pmax = fmaxf(pmax, s0[r]);
#pragma unroll
    for (int r = 0; r < 16; r++) pmax = fmaxf(pmax, s1[r]);
    pmax = fmaxf(pmax, __shfl_xor(pmax, 32));
    pmax *= csc;

    // defer-max (T13): only rescale when a row's max grew by > 8 (base-2 domain)
    if (__any(pmax > m + 8.f)) {
      float mn = fmaxf(m, pmax);
      float a = exp2f(m - mn);
      m = mn;
      lsum *= a;
#pragma unroll
      for (int r = 0; r < 16; r++) { o0[r] *= a; o1[r] *= a; }
    }

    // P = exp2(S*csc - m) in place; row sum
    float rs = 0.f;
#pragma unroll
    for (int r = 0; r < 16; r++) {
      s0[r] = exp2f(fmaf(s0[r], csc, -m));
      s1[r] = exp2f(fmaf(s1[r], csc, -m));
      rs += s0[r] + s1[r];
    }
    rs += __shfl_xor(rs, 32);
    lsum += rs;

    // P -> bf16 B-fragments (T12: cvt_pk + permlane32_swap, all in-register)
    union Frag { bf16x8 v; unsigned u[4]; } pb[4];
#pragma unroll
    for (int ct = 0; ct < 2; ct++) {
      const f32x16& p = (ct == 0) ? s0 : s1;
#pragma unroll
      for (int ksl = 0; ksl < 2; ksl++) {
        const int b = ksl * 8;
        unsigned a0, b0, a1, b1;
        asm("v_cvt_pk_bf16_f32 %0, %1, %2" : "=v"(a0) : "v"(p[b+0]), "v"(p[b+1]));
        asm("v_cvt_pk_bf16_f32 %0, %1, %2" : "=v"(b0) : "v"(p[b+4]), "v"(p[b+5]));
        asm("v_cvt_pk_bf16_f32 %0, %1, %2" : "=v"(a1) : "v"(p[b+2]), "v"(p[b+3]));
        asm("v_cvt_pk_bf16_f32 %0, %1, %2" : "=v"(b1) : "v"(p[b+6]), "v"(p[b+7]));
        plane32_swap(a0, b0);
        plane32_swap(a1, b1);
        Frag& f = pb[ct * 2 + ksl];
        f.u[0] = a0; f.u[1] = a1; f.u[2] = b0; f.u[3] = b1;
      }
    }

    // O^T[d][q] += V^T[d][kv] * P^T[kv][q]
#pragma unroll
    for (int kvs = 0; kvs < 4; kvs++) {
      o0 = __builtin_amdgcn_mfma_f32_32x32x16_bf16(vf0[kvs], pb[kvs].v, o0, 0, 0, 0);
      o1 = __builtin_amdgcn_mfma_f32_32x32x16_bf16(vf1[kvs], pb[kvs].v, o1, 0, 0, 0);
    }

    kp += 64 * DK_;   // next 64 kv rows
    vp += 64;         // next 64 kv cols of V^T
  }

  // epilogue: ctx[b][s][h][d] bf16; lane holds q=q0+l31, d = dt*32 + 8g + 4hi + 0..3
  float inv = 1.f / lsum;
  int bb = bh >> 4, h = bh & 15;
  int srow = q0 + l31;
  ushort_t* cp = ctx + (((size_t)bb * S_ + srow) * H_ + h) * DK_;
#pragma unroll
  for (int dt = 0; dt < 2; dt++) {
    const f32x16& o = (dt == 0) ? o0 : o1;
#pragma unroll
    for (int g = 0; g < 4; g++) {
      ushort4 w;
      w.x = f2bf(o[4*g+0] * inv); w.y = f2bf(o[4*g+1] * inv);
      w.z = f2bf(o[4*g+2] * inv); w.w = f2bf(o[4*g+3] * inv);
      *(ushort4*)(cp + dt * 32 + 8 * g + 4 * hi) = w;
    }
  }
}

extern "C" void kernel_launch(void* const* d_in, const int* in_sizes, int n_in,
                              void* d_out, int out_size, void* d_ws, size_t ws_size,
                              hipStream_t stream) {
  const float* query = (const float*)d_in[0];
  const float* key   = (const float*)d_in[1];
  const float* value = (const float*)d_in[2];
  const float* Wq = (const float*)d_in[4];
  const float* bq = (const float*)d_in[5];
  const float* Wk = (const float*)d_in[6];
  const float* bk = (const float*)d_in[7];
  const float* Wv = (const float*)d_in[8];
  const float* bv = (const float*)d_in[9];
  const float* Wo = (const float*)d_in[10];
  const float* bo = (const float*)d_in[11];

  char* ws = (char*)d_ws;
  const size_t MD = (size_t)M_ * D_;      // 8388608 elements
  const size_t DD = (size_t)D_ * D_;
  ushort_t* xb  = (ushort_t*)ws;                              // [3][M][D] bf16 inputs
  ushort_t* wt  = (ushort_t*)(ws + 3 * MD * 2);               // [4][D][D] bf16 W^T
  ushort_t* Qp  = (ushort_t*)(ws + 3 * MD * 2 + 4 * DD * 2);  // [B,H,S,DK]
  ushort_t* Kp  = Qp + MD;
  ushort_t* Vp  = Kp + MD;
  ushort_t* Vt  = xb + MD;   // reuse xb[1] (key copy dead after K-proj)
  ushort_t* ctx = xb;        // reuse xb[0] (query copy dead after Q-proj)

  k_convert<<<2048, 256, 0, stream>>>(query, key, value, xb);
  k_wtrans<<<1024, 256, 0, stream>>>(Wq, Wk, Wv, Wo, wt);
  k_gemm<0><<<512, 256, 0, stream>>>(xb,          wt,          bq, Qp);
  k_gemm<0><<<512, 256, 0, stream>>>(xb + MD,     wt + DD,     bk, Kp);
  k_gemm<0><<<512, 256, 0, stream>>>(xb + 2 * MD, wt + 2 * DD, bv, Vp);
  k_vtrans<<<2048, 256, 0, stream>>>(Vp, Vt);
  k_attn<<<1024, 256, 0, stream>>>(Qp, Kp, Vt, ctx);
  k_gemm<1><<<512, 256, 0, stream>>>(ctx, wt + 3 * DD, bo, (float*)d_out);
}

// Round 4
// 418.412 us; speedup vs baseline: 1.3537x; 1.2857x over previous
//
#include <hip/hip_runtime.h>
#include <hip/hip_bf16.h>

#define B_ 4
#define S_ 2048
#define D_ 1024
#define H_ 16
#define DK_ 64
#define M_ (B_*S_)   // 8192

typedef unsigned short ushort_t;
typedef __bf16 bf16x8 __attribute__((ext_vector_type(8)));
typedef float f32x4 __attribute__((ext_vector_type(4)));
typedef float f32x16 __attribute__((ext_vector_type(16)));
typedef unsigned uint2v __attribute__((ext_vector_type(2)));

__device__ __forceinline__ ushort_t f2bf(float f) {
  union { float f; unsigned u; } v; v.f = f;
  unsigned u = v.u;
  return (ushort_t)((u + 0x7fffu + ((u >> 16) & 1u)) >> 16);
}

__device__ __forceinline__ void gload16(const void* g, void* l) {
  __builtin_amdgcn_global_load_lds(
      (const __attribute__((address_space(1))) unsigned int*)g,
      (__attribute__((address_space(3))) unsigned int*)l, 16, 0, 0);
}

// swap(a.lane[i+32], b.lane[i]) — gfx950 v_permlane32_swap_b32
__device__ __forceinline__ void plane32_swap(unsigned& a, unsigned& b) {
#if __has_builtin(__builtin_amdgcn_permlane32_swap)
  uint2v r = __builtin_amdgcn_permlane32_swap(a, b, false, false);
  a = r.x; b = r.y;
#else
  unsigned pa = __shfl_xor((int)a, 32), pb = __shfl_xor((int)b, 32);
  bool hi = (threadIdx.x & 32) != 0;
  unsigned na = hi ? pb : a;
  unsigned nb = hi ? b : pa;
  a = na; b = nb;
#endif
}

// ---------------- convert q,k,v f32 -> bf16 ----------------
__global__ void k_convert(const float* __restrict__ q, const float* __restrict__ k,
                          const float* __restrict__ v, ushort_t* __restrict__ out) {
  const int n4 = (M_*D_) / 4;  // 2^21 per array
  int tid = blockIdx.x * blockDim.x + threadIdx.x;
  int stride = gridDim.x * blockDim.x;
  for (int i = tid; i < 3 * n4; i += stride) {
    int a = i >> 21;
    int r = i & (n4 - 1);
    const float4* src = (const float4*)(a == 0 ? q : (a == 1 ? k : v));
    float4 x = src[r];
    ushort4 o;
    o.x = f2bf(x.x); o.y = f2bf(x.y); o.z = f2bf(x.z); o.w = f2bf(x.w);
    *(ushort4*)(out + (size_t)a * (M_*D_) + (size_t)r * 4) = o;
  }
}

// ---------------- weight transpose+convert: Wt[n][k] = bf16(W[k][n]) ----------------
__global__ void k_wtrans(const float* __restrict__ Wq, const float* __restrict__ Wk,
                         const float* __restrict__ Wv, const float* __restrict__ Wo,
                         ushort_t* __restrict__ wt) {
  __shared__ ushort_t ls[64][72];
  int bid = blockIdx.x;
  int w = bid >> 8;
  int tile = bid & 255;
  int tk = (tile >> 4) * 64;
  int tn = (tile & 15) * 64;
  const float* W = (w == 0 ? Wq : w == 1 ? Wk : w == 2 ? Wv : Wo);
  int t = threadIdx.x;
  int r = t >> 4;
  int c = (t & 15) * 4;
#pragma unroll
  for (int i = 0; i < 4; i++) {
    int rr = r + i * 16;
    float4 x = *(const float4*)(W + (size_t)(tk + rr) * D_ + tn + c);
    ls[rr][c] = f2bf(x.x); ls[rr][c+1] = f2bf(x.y);
    ls[rr][c+2] = f2bf(x.z); ls[rr][c+3] = f2bf(x.w);
  }
  __syncthreads();
  ushort_t* dst = wt + (size_t)w * D_ * D_;
#pragma unroll
  for (int i = 0; i < 4; i++) {
    int rr = r + i * 16;
    ushort4 o;
    o.x = ls[c+0][rr]; o.y = ls[c+1][rr]; o.z = ls[c+2][rr]; o.w = ls[c+3][rr];
    *(ushort4*)(dst + (size_t)(tn + rr) * D_ + tk + c) = o;
  }
}

// ---------------- GEMM: C[M,1024] = A[M,1024] @ Bt[1024,1024]^T + bias ----------------
// 2-phase double-buffered: issue next K-step's global_load_lds before computing current.
// EPI 0: bf16 out to [B,H,S,DK];  EPI 1: f32 out row-major [M,1024]
template<int EPI>
__global__ __launch_bounds__(256, 2) void k_gemm(
    const ushort_t* __restrict__ A, const ushort_t* __restrict__ Bt,
    const float* __restrict__ bias, void* __restrict__ out) {
  __shared__ ushort_t As[2][128 * 32];
  __shared__ ushort_t Bs[2][128 * 32];
  const int K = D_;
  int nwg = gridDim.x;           // 512, divisible by 8
  int cpx = nwg >> 3;
  int bid = blockIdx.x;
  int wg = (bid & 7) * cpx + (bid >> 3);   // XCD-aware swizzle (bijective)
  int by = wg >> 3;
  int bx = wg & 7;
  int m0 = by * 128, n0 = bx * 128;
  int t = threadIdx.x;
  int l = t & 63, wid = t >> 6;
  int wy = wid >> 1, wx = wid & 1;
  int lr = l & 15, lg = l >> 4;

  f32x4 acc[4][4] = {};
  const ushort_t* ga0 = A  + (size_t)(m0 + (t >> 2)) * K + (t & 3) * 8;
  const ushort_t* gb0 = Bt + (size_t)(n0 + (t >> 2)) * K + (t & 3) * 8;

  // prologue: stage k0=0 into buf 0
  {
    ushort_t* lA = As[0] + wid * 512;
    ushort_t* lB = Bs[0] + wid * 512;
    gload16(ga0, lA);
    gload16(ga0 + (size_t)64 * K, lA + 2048);
    gload16(gb0, lB);
    gload16(gb0 + (size_t)64 * K, lB + 2048);
  }
  __syncthreads();

  int cur = 0;
  for (int k0 = 0; k0 < K; k0 += 32) {
    if (k0 + 32 < K) {   // prefetch next K-step into other buffer (overlaps MFMA below)
      int nb = cur ^ 1;
      ushort_t* lA = As[nb] + wid * 512;
      ushort_t* lB = Bs[nb] + wid * 512;
      gload16(ga0 + k0 + 32, lA);
      gload16(ga0 + (size_t)64 * K + k0 + 32, lA + 2048);
      gload16(gb0 + k0 + 32, lB);
      gload16(gb0 + (size_t)64 * K + k0 + 32, lB + 2048);
    }
    bf16x8 a[4], b[4];
#pragma unroll
    for (int mi = 0; mi < 4; mi++)
      a[mi] = *(const bf16x8*)(As[cur] + (wy * 64 + mi * 16 + lr) * 32 + lg * 8);
#pragma unroll
    for (int ni = 0; ni < 4; ni++)
      b[ni] = *(const bf16x8*)(Bs[cur] + (wx * 64 + ni * 16 + lr) * 32 + lg * 8);
#pragma unroll
    for (int mi = 0; mi < 4; mi++)
#pragma unroll
      for (int ni = 0; ni < 4; ni++)
        acc[mi][ni] = __builtin_amdgcn_mfma_f32_16x16x32_bf16(a[mi], b[ni], acc[mi][ni], 0, 0, 0);
    __syncthreads();   // drains prefetch vmcnt + protects buffer reuse
    cur ^= 1;
  }
#pragma unroll
  for (int mi = 0; mi < 4; mi++)
#pragma unroll
    for (int ni = 0; ni < 4; ni++) {
      int col = n0 + wx * 64 + ni * 16 + lr;
      float bs = bias[col];
#pragma unroll
      for (int j = 0; j < 4; j++) {
        int row = m0 + wy * 64 + mi * 16 + lg * 4 + j;
        float val = acc[mi][ni][j] + bs;
        if (EPI == 0) {
          int bi = row >> 11, s = row & 2047;
          int h = col >> 6, d = col & 63;
          ((ushort_t*)out)[(((size_t)bi * H_ + h) * S_ + s) * DK_ + d] = f2bf(val);
        } else {
          ((float*)out)[(size_t)row * D_ + col] = val;
        }
      }
    }
}

// ---------------- V transpose per (b,h): Vt[d][s] = Vp[s][d] ----------------
__global__ void k_vtrans(const ushort_t* __restrict__ Vp, ushort_t* __restrict__ Vt) {
  __shared__ ushort_t ls[64][72];
  int bid = blockIdx.x;
  int bh = bid >> 5;
  int t0 = (bid & 31) * 64;
  int t = threadIdx.x;
  const ushort_t* src = Vp + (size_t)bh * S_ * DK_;
#pragma unroll
  for (int i = 0; i < 2; i++) {
    int r = i * 32 + (t >> 3);
    int c = (t & 7) * 8;
    *(float4*)&ls[r][c] = *(const float4*)(src + (size_t)(t0 + r) * DK_ + c);
  }
  __syncthreads();
  ushort_t* dst = Vt + (size_t)bh * DK_ * S_;
#pragma unroll
  for (int i = 0; i < 2; i++) {
    int d = i * 32 + (t >> 3);
    int c = (t & 7) * 8;
    union { ushort_t u[8]; float4 v; } tmp;
#pragma unroll
    for (int j = 0; j < 8; j++) tmp.u[j] = ls[c + j][d];
    *(float4*)(dst + (size_t)d * S_ + t0 + c) = tmp.v;
  }
}

// ---------------- flash attention: swapped-operand 32x32, LDS-staged K/V ----------
// grid: 1024 blocks; bid = qt*64 + bh. 4 waves/block, each wave owns 32 q rows.
// KVBLK=64. K/V tiles staged once per block (shared by 4 waves), double-buffered,
// prefetched one tile ahead. XOR-swizzle (row&7) via pre-swizzled global source.
__global__ __launch_bounds__(256, 2) void k_attn(
    const ushort_t* __restrict__ Qp, const ushort_t* __restrict__ Kp,
    const ushort_t* __restrict__ Vt, ushort_t* __restrict__ ctx) {
  __shared__ ushort_t Ks[2][64 * 64];   // [kv][dk] swizzled, 8KB each
  __shared__ ushort_t Vs[2][64 * 64];   // [d][t]  swizzled
  int bid = blockIdx.x;
  int bh = bid & 63;
  int qt = bid >> 6;
  int t = threadIdx.x;
  int l = t & 63, wid = t >> 6;
  int l31 = l & 31, hi = l >> 5;
  const float csc = 0.125f * 1.44269504f;  // scale * log2(e)

  const ushort_t* Qb = Qp + (size_t)bh * S_ * DK_;
  const ushort_t* Kb = Kp + (size_t)bh * S_ * DK_;
  const ushort_t* Vb = Vt + (size_t)bh * DK_ * S_;

  int q0 = qt * 128 + wid * 32;
  // Q as B-fragments (col q = l31, k-rows dk = ks*16 + hi*8 + j)
  bf16x8 qf[4];
  const ushort_t* qp = Qb + (size_t)(q0 + l31) * DK_ + hi * 8;
#pragma unroll
  for (int ks = 0; ks < 4; ks++) qf[ks] = *(const bf16x8*)(qp + ks * 16);

  // staging geometry: tile = 64 rows x 8 chunks(16B) = 512 chunks; thread t
  // handles chunks {t, t+256}. LDS dest linear (wave-uniform base + lane*16);
  // global source pre-swizzled: chunk slot c holds data chunk c^(row&7).
  int sr0 = t >> 3;           // row of first chunk (0..31)
  int sc0 = t & 7;            // chunk slot
  int sr1 = sr0 + 32;         // row of second chunk
  const ushort_t* kg0 = Kb + (size_t)sr0 * DK_ + (sc0 ^ (sr0 & 7)) * 8;
  const ushort_t* kg1 = Kb + (size_t)sr1 * DK_ + (sc0 ^ (sr1 & 7)) * 8;
  const ushort_t* vg0 = Vb + (size_t)sr0 * S_ + (sc0 ^ (sr0 & 7)) * 8;
  const ushort_t* vg1 = Vb + (size_t)sr1 * S_ + (sc0 ^ (sr1 & 7)) * 8;

  f32x16 o0 = {}, o1 = {};
  float m = -1e30f, lsum = 0.f;

  // prologue: stage tile 0 into buf 0
  {
    ushort_t* lK = Ks[0] + wid * 512;
    ushort_t* lV = Vs[0] + wid * 512;
    gload16(kg0, lK);
    gload16(kg1, lK + 2048);
    gload16(vg0, lV);
    gload16(vg1, lV + 2048);
  }
  __syncthreads();

  int cur = 0;
  for (int t0 = 0; t0 < S_; t0 += 64) {
    if (t0 + 64 < S_) {   // prefetch next KV tile (overlaps compute below)
      int nb = cur ^ 1;
      ushort_t* lK = Ks[nb] + wid * 512;
      ushort_t* lV = Vs[nb] + wid * 512;
      gload16(kg0 + (size_t)(t0 + 64) * DK_, lK);
      gload16(kg1 + (size_t)(t0 + 64) * DK_, lK + 2048);
      gload16(vg0 + t0 + 64, lV);
      gload16(vg1 + t0 + 64, lV + 2048);
    }

    // fragment loads from swizzled LDS: row r, chunk (hi+2ks)^(r&7)
    bf16x8 kf0[4], kf1[4], vf0[4], vf1[4];
    {
      const ushort_t* Kc = Ks[cur];
      const ushort_t* Vc = Vs[cur];
      int r0 = l31, r1 = l31 + 32;
#pragma unroll
      for (int ks = 0; ks < 4; ks++) {
        int c = hi + 2 * ks;
        kf0[ks] = *(const bf16x8*)(Kc + r0 * 64 + ((c ^ (r0 & 7)) * 8));
        kf1[ks] = *(const bf16x8*)(Kc + r1 * 64 + ((c ^ (r1 & 7)) * 8));
        vf0[ks] = *(const bf16x8*)(Vc + r0 * 64 + ((c ^ (r0 & 7)) * 8));
        vf1[ks] = *(const bf16x8*)(Vc + r1 * 64 + ((c ^ (r1 & 7)) * 8));
      }
    }

    // S^T[kv][q] = K[kv][dk] * Q^T[dk][q]
    f32x16 s0 = {}, s1 = {};
#pragma unroll
    for (int ks = 0; ks < 4; ks++) {
      s0 = __builtin_amdgcn_mfma_f32_32x32x16_bf16(kf0[ks], qf[ks], s0, 0, 0, 0);
      s1 = __builtin_amdgcn_mfma_f32_32x32x16_bf16(kf1[ks], qf[ks], s1, 0, 0, 0);
    }

    // row max via max3 tree (lane owns q=l31; partner l^32 has other kv rows)
    float t0m = fmaxf(fmaxf(s0[0], s0[1]), s0[2]);
    float t1m = fmaxf(fmaxf(s0[3], s0[4]), s0[5]);
    float t2m = fmaxf(fmaxf(s0[6], s0[7]), s0[8]);
    float t3m = fmaxf(fmaxf(s0[9], s0[10]), s0[11]);
    float t4m = fmaxf(fmaxf(s0[12], s0[13]), s0[14]);
    float t5m = fmaxf(fmaxf(s0[15], s1[0]), s1[1]);
    float t6m = fmaxf(fmaxf(s1[2], s1[3]), s1[4]);
    float t7m = fmaxf(fmaxf(s1[5], s1[6]), s1[7]);
    float t8m = fmaxf(fmaxf(s1[8], s1[9]), s1[10]);
    float t9m = fmaxf(fmaxf(s1[11], s1[12]), s1[13]);
    float tam = fmaxf(s1[14], s1[15]);
    t0m = fmaxf(fmaxf(t0m, t1m), t2m);
    t3m = fmaxf(fmaxf(t3m, t4m), t5m);
    t6m = fmaxf(fmaxf(t6m, t7m), t8m);
    t9m = fmaxf(t9m, tam);
    float pmax = fmaxf(fmaxf(t0m, t3m), fmaxf(t6m, t9m));
    pmax = fmaxf(pmax, __shfl_xor(pmax, 32));
    pmax *= csc;

    // defer-max (T13): only rescale when a row's max grew by > 8 (base-2 domain)
    if (__any(pmax > m + 8.f)) {
      float mn = fmaxf(m, pmax);
      float a = exp2f(m - mn);
      m = mn;
      lsum *= a;
#pragma unroll
      for (int r = 0; r < 16; r++) { o0[r] *= a; o1[r] *= a; }
    }

    // P = exp2(S*csc - m) in place; row sum
    float rs = 0.f;
#pragma unroll
    for (int r = 0; r < 16; r++) {
      s0[r] = exp2f(fmaf(s0[r], csc, -m));
      s1[r] = exp2f(fmaf(s1[r], csc, -m));
      rs += s0[r] + s1[r];
    }
    rs += __shfl_xor(rs, 32);
    lsum += rs;

    // P -> bf16 B-fragments (T12: cvt_pk + permlane32_swap, all in-register)
    union Frag { bf16x8 v; unsigned u[4]; } pb[4];
#pragma unroll
    for (int ct = 0; ct < 2; ct++) {
      const f32x16& p = (ct == 0) ? s0 : s1;
#pragma unroll
      for (int ksl = 0; ksl < 2; ksl++) {
        const int b = ksl * 8;
        unsigned a0, b0, a1, b1;
        asm("v_cvt_pk_bf16_f32 %0, %1, %2" : "=v"(a0) : "v"(p[b+0]), "v"(p[b+1]));
        asm("v_cvt_pk_bf16_f32 %0, %1, %2" : "=v"(b0) : "v"(p[b+4]), "v"(p[b+5]));
        asm("v_cvt_pk_bf16_f32 %0, %1, %2" : "=v"(a1) : "v"(p[b+2]), "v"(p[b+3]));
        asm("v_cvt_pk_bf16_f32 %0, %1, %2" : "=v"(b1) : "v"(p[b+6]), "v"(p[b+7]));
        plane32_swap(a0, b0);
        plane32_swap(a1, b1);
        Frag& f = pb[ct * 2 + ksl];
        f.u[0] = a0; f.u[1] = a1; f.u[2] = b0; f.u[3] = b1;
      }
    }

    // O^T[d][q] += V^T[d][kv] * P^T[kv][q]
#pragma unroll
    for (int kvs = 0; kvs < 4; kvs++) {
      o0 = __builtin_amdgcn_mfma_f32_32x32x16_bf16(vf0[kvs], pb[kvs].v, o0, 0, 0, 0);
      o1 = __builtin_amdgcn_mfma_f32_32x32x16_bf16(vf1[kvs], pb[kvs].v, o1, 0, 0, 0);
    }

    __syncthreads();   // drains prefetch vmcnt; protects buffer reuse
    cur ^= 1;
  }

  // epilogue: ctx[b][s][h][d] bf16; lane holds q=q0+l31, d = dt*32 + 8g + 4hi + 0..3
  float inv = 1.f / lsum;
  int bb = bh >> 4, h = bh & 15;
  int srow = q0 + l31;
  ushort_t* cp = ctx + (((size_t)bb * S_ + srow) * H_ + h) * DK_;
#pragma unroll
  for (int dt = 0; dt < 2; dt++) {
    const f32x16& o = (dt == 0) ? o0 : o1;
#pragma unroll
    for (int g = 0; g < 4; g++) {
      ushort4 w;
      w.x = f2bf(o[4*g+0] * inv); w.y = f2bf(o[4*g+1] * inv);
      w.z = f2bf(o[4*g+2] * inv); w.w = f2bf(o[4*g+3] * inv);
      *(ushort4*)(cp + dt * 32 + 8 * g + 4 * hi) = w;
    }
  }
}

extern "C" void kernel_launch(void* const* d_in, const int* in_sizes, int n_in,
                              void* d_out, int out_size, void* d_ws, size_t ws_size,
                              hipStream_t stream) {
  const float* query = (const float*)d_in[0];
  const float* key   = (const float*)d_in[1];
  const float* value = (const float*)d_in[2];
  const float* Wq = (const float*)d_in[4];
  const float* bq = (const float*)d_in[5];
  const float* Wk = (const float*)d_in[6];
  const float* bk = (const float*)d_in[7];
  const float* Wv = (const float*)d_in[8];
  const float* bv = (const float*)d_in[9];
  const float* Wo = (const float*)d_in[10];
  const float* bo = (const float*)d_in[11];

  char* ws = (char*)d_ws;
  const size_t MD = (size_t)M_ * D_;      // 8388608 elements
  const size_t DD = (size_t)D_ * D_;
  ushort_t* xb  = (ushort_t*)ws;                              // [3][M][D] bf16 inputs
  ushort_t* wt  = (ushort_t*)(ws + 3 * MD * 2);               // [4][D][D] bf16 W^T
  ushort_t* Qp  = (ushort_t*)(ws + 3 * MD * 2 + 4 * DD * 2);  // [B,H,S,DK]
  ushort_t* Kp  = Qp + MD;
  ushort_t* Vp  = Kp + MD;
  ushort_t* Vt  = xb + MD;   // reuse xb[1] (key copy dead after K-proj)
  ushort_t* ctx = xb;        // reuse xb[0] (query copy dead after Q-proj)

  k_convert<<<2048, 256, 0, stream>>>(query, key, value, xb);
  k_wtrans<<<1024, 256, 0, stream>>>(Wq, Wk, Wv, Wo, wt);
  k_gemm<0><<<512, 256, 0, stream>>>(xb,          wt,          bq, Qp);
  k_gemm<0><<<512, 256, 0, stream>>>(xb + MD,     wt + DD,     bk, Kp);
  k_gemm<0><<<512, 256, 0, stream>>>(xb + 2 * MD, wt + 2 * DD, bv, Vp);
  k_vtrans<<<2048, 256, 0, stream>>>(Vp, Vt);
  k_attn<<<1024, 256, 0, stream>>>(Qp, Kp, Vt, ctx);
  k_gemm<1><<<512, 256, 0, stream>>>(ctx, wt + 3 * DD, bo, (float*)d_out);
}

// Round 5
// 394.002 us; speedup vs baseline: 1.4375x; 1.0620x over previous
//
#include <hip/hip_runtime.h>
#include <hip/hip_bf16.h>

#define B_ 4
#define S_ 2048
#define D_ 1024
#define H_ 16
#define DK_ 64
#define M_ (B_*S_)   // 8192

typedef unsigned short ushort_t;
typedef __bf16 bf16x8 __attribute__((ext_vector_type(8)));
typedef float f32x4 __attribute__((ext_vector_type(4)));
typedef float f32x16 __attribute__((ext_vector_type(16)));
typedef unsigned uint2v __attribute__((ext_vector_type(2)));

__device__ __forceinline__ ushort_t f2bf(float f) {
  union { float f; unsigned u; } v; v.f = f;
  unsigned u = v.u;
  return (ushort_t)((u + 0x7fffu + ((u >> 16) & 1u)) >> 16);
}

__device__ __forceinline__ void gload16(const void* g, void* l) {
  __builtin_amdgcn_global_load_lds(
      (const __attribute__((address_space(1))) unsigned int*)g,
      (__attribute__((address_space(3))) unsigned int*)l, 16, 0, 0);
}

// swap(a.lane[i+32], b.lane[i]) — gfx950 v_permlane32_swap_b32
__device__ __forceinline__ void plane32_swap(unsigned& a, unsigned& b) {
#if __has_builtin(__builtin_amdgcn_permlane32_swap)
  uint2v r = __builtin_amdgcn_permlane32_swap(a, b, false, false);
  a = r.x; b = r.y;
#else
  unsigned pa = __shfl_xor((int)a, 32), pb = __shfl_xor((int)b, 32);
  bool hi = (threadIdx.x & 32) != 0;
  unsigned na = hi ? pb : a;
  unsigned nb = hi ? b : pa;
  a = na; b = nb;
#endif
}

// ---------------- convert q,k,v f32 -> bf16 ----------------
__global__ void k_convert(const float* __restrict__ q, const float* __restrict__ k,
                          const float* __restrict__ v, ushort_t* __restrict__ out) {
  const int n4 = (M_*D_) / 4;  // 2^21 per array
  int tid = blockIdx.x * blockDim.x + threadIdx.x;
  int stride = gridDim.x * blockDim.x;
  for (int i = tid; i < 3 * n4; i += stride) {
    int a = i >> 21;
    int r = i & (n4 - 1);
    const float4* src = (const float4*)(a == 0 ? q : (a == 1 ? k : v));
    float4 x = src[r];
    ushort4 o;
    o.x = f2bf(x.x); o.y = f2bf(x.y); o.z = f2bf(x.z); o.w = f2bf(x.w);
    *(ushort4*)(out + (size_t)a * (M_*D_) + (size_t)r * 4) = o;
  }
}

// ---------------- weight transpose+convert: Wt[n][k] = bf16(W[k][n]) ----------------
__global__ void k_wtrans(const float* __restrict__ Wq, const float* __restrict__ Wk,
                         const float* __restrict__ Wv, const float* __restrict__ Wo,
                         ushort_t* __restrict__ wt) {
  __shared__ ushort_t ls[64][72];
  int bid = blockIdx.x;
  int w = bid >> 8;
  int tile = bid & 255;
  int tk = (tile >> 4) * 64;
  int tn = (tile & 15) * 64;
  const float* W = (w == 0 ? Wq : w == 1 ? Wk : w == 2 ? Wv : Wo);
  int t = threadIdx.x;
  int r = t >> 4;
  int c = (t & 15) * 4;
#pragma unroll
  for (int i = 0; i < 4; i++) {
    int rr = r + i * 16;
    float4 x = *(const float4*)(W + (size_t)(tk + rr) * D_ + tn + c);
    ls[rr][c] = f2bf(x.x); ls[rr][c+1] = f2bf(x.y);
    ls[rr][c+2] = f2bf(x.z); ls[rr][c+3] = f2bf(x.w);
  }
  __syncthreads();
  ushort_t* dst = wt + (size_t)w * D_ * D_;
#pragma unroll
  for (int i = 0; i < 4; i++) {
    int rr = r + i * 16;
    ushort4 o;
    o.x = ls[c+0][rr]; o.y = ls[c+1][rr]; o.z = ls[c+2][rr]; o.w = ls[c+3][rr];
    *(ushort4*)(dst + (size_t)(tn + rr) * D_ + tk + c) = o;
  }
}

// ---------------- fused QKV GEMM: N=3072, per-block A selected by col-block -----
// col block w = 0/1/2 -> A = xq/xk/xv, Bt = Wt_w, bias = bq/bk/bv.
// Q,K out: [B,H,S,DK] bf16.  V out: DIRECTLY TRANSPOSED Vt[bh][d][s] bf16.
__global__ __launch_bounds__(256, 2) void k_gemm_qkv(
    const ushort_t* __restrict__ X, const ushort_t* __restrict__ Wt,
    const float* __restrict__ bq, const float* __restrict__ bk,
    const float* __restrict__ bv,
    ushort_t* __restrict__ Qp, ushort_t* __restrict__ Kp,
    ushort_t* __restrict__ VtT) {
  __shared__ ushort_t As[2][128 * 32];
  __shared__ ushort_t Bs[2][128 * 32];
  const int K = D_;
  const size_t MD = (size_t)M_ * D_;
  const size_t DD = (size_t)D_ * D_;
  int nwg = gridDim.x;           // 1536, divisible by 8
  int cpx = nwg >> 3;            // 192
  int bid = blockIdx.x;
  int wg = (bid & 7) * cpx + (bid >> 3);   // XCD-aware swizzle (bijective)
  int by = wg / 24;              // 0..63  (row tile; 24 consecutive wg share A panel)
  int bx = wg % 24;              // 0..23  (col tile)
  int w = bx >> 3;               // which projection
  int m0 = by * 128, n0 = (bx & 7) * 128;  // n0 local within [0,1024)
  int t = threadIdx.x;
  int l = t & 63, wid = t >> 6;
  int wy = wid >> 1, wx = wid & 1;
  int lr = l & 15, lg = l >> 4;

  const ushort_t* A  = X  + (size_t)w * MD;
  const ushort_t* Bt = Wt + (size_t)w * DD;

  f32x4 acc[4][4] = {};
  const ushort_t* ga0 = A  + (size_t)(m0 + (t >> 2)) * K + (t & 3) * 8;
  const ushort_t* gb0 = Bt + (size_t)(n0 + (t >> 2)) * K + (t & 3) * 8;

  {
    ushort_t* lA = As[0] + wid * 512;
    ushort_t* lB = Bs[0] + wid * 512;
    gload16(ga0, lA);
    gload16(ga0 + (size_t)64 * K, lA + 2048);
    gload16(gb0, lB);
    gload16(gb0 + (size_t)64 * K, lB + 2048);
  }
  __syncthreads();

  int cur = 0;
  for (int k0 = 0; k0 < K; k0 += 32) {
    if (k0 + 32 < K) {
      int nb = cur ^ 1;
      ushort_t* lA = As[nb] + wid * 512;
      ushort_t* lB = Bs[nb] + wid * 512;
      gload16(ga0 + k0 + 32, lA);
      gload16(ga0 + (size_t)64 * K + k0 + 32, lA + 2048);
      gload16(gb0 + k0 + 32, lB);
      gload16(gb0 + (size_t)64 * K + k0 + 32, lB + 2048);
    }
    bf16x8 a[4], b[4];
#pragma unroll
    for (int mi = 0; mi < 4; mi++)
      a[mi] = *(const bf16x8*)(As[cur] + (wy * 64 + mi * 16 + lr) * 32 + lg * 8);
#pragma unroll
    for (int ni = 0; ni < 4; ni++)
      b[ni] = *(const bf16x8*)(Bs[cur] + (wx * 64 + ni * 16 + lr) * 32 + lg * 8);
#pragma unroll
    for (int mi = 0; mi < 4; mi++)
#pragma unroll
      for (int ni = 0; ni < 4; ni++)
        acc[mi][ni] = __builtin_amdgcn_mfma_f32_16x16x32_bf16(a[mi], b[ni], acc[mi][ni], 0, 0, 0);
    __syncthreads();
    cur ^= 1;
  }

  const float* bp = (w == 0 ? bq : w == 1 ? bk : bv);
#pragma unroll
  for (int mi = 0; mi < 4; mi++)
#pragma unroll
    for (int ni = 0; ni < 4; ni++) {
      int cl = n0 + wx * 64 + ni * 16 + lr;   // 0..1023
      float bs = bp[cl];
      int h = cl >> 6, d = cl & 63;
      int row0 = m0 + wy * 64 + mi * 16 + lg * 4;
      int bi = row0 >> 11, s0 = row0 & 2047;
      if (w == 2) {
        // V: write transposed Vt[bh][d][s], j runs over s -> vector store
        ushort4 o;
        o.x = f2bf(acc[mi][ni][0] + bs); o.y = f2bf(acc[mi][ni][1] + bs);
        o.z = f2bf(acc[mi][ni][2] + bs); o.w = f2bf(acc[mi][ni][3] + bs);
        *(ushort4*)(VtT + (((size_t)bi * H_ + h) * DK_ + d) * S_ + s0) = o;
      } else {
        ushort_t* dst = (w == 0 ? Qp : Kp);
#pragma unroll
        for (int j = 0; j < 4; j++) {
          float val = acc[mi][ni][j] + bs;
          dst[(((size_t)bi * H_ + h) * S_ + (s0 + j)) * DK_ + d] = f2bf(val);
        }
      }
    }
}

// ---------------- final GEMM: C[M,1024] = ctx @ Wo^T + bo, f32 out ---------------
__global__ __launch_bounds__(256, 2) void k_gemm_o(
    const ushort_t* __restrict__ A, const ushort_t* __restrict__ Bt,
    const float* __restrict__ bias, float* __restrict__ out) {
  __shared__ ushort_t As[2][128 * 32];
  __shared__ ushort_t Bs[2][128 * 32];
  const int K = D_;
  int nwg = gridDim.x;           // 512
  int cpx = nwg >> 3;
  int bid = blockIdx.x;
  int wg = (bid & 7) * cpx + (bid >> 3);
  int by = wg >> 3;
  int bx = wg & 7;
  int m0 = by * 128, n0 = bx * 128;
  int t = threadIdx.x;
  int l = t & 63, wid = t >> 6;
  int wy = wid >> 1, wx = wid & 1;
  int lr = l & 15, lg = l >> 4;

  f32x4 acc[4][4] = {};
  const ushort_t* ga0 = A  + (size_t)(m0 + (t >> 2)) * K + (t & 3) * 8;
  const ushort_t* gb0 = Bt + (size_t)(n0 + (t >> 2)) * K + (t & 3) * 8;

  {
    ushort_t* lA = As[0] + wid * 512;
    ushort_t* lB = Bs[0] + wid * 512;
    gload16(ga0, lA);
    gload16(ga0 + (size_t)64 * K, lA + 2048);
    gload16(gb0, lB);
    gload16(gb0 + (size_t)64 * K, lB + 2048);
  }
  __syncthreads();

  int cur = 0;
  for (int k0 = 0; k0 < K; k0 += 32) {
    if (k0 + 32 < K) {
      int nb = cur ^ 1;
      ushort_t* lA = As[nb] + wid * 512;
      ushort_t* lB = Bs[nb] + wid * 512;
      gload16(ga0 + k0 + 32, lA);
      gload16(ga0 + (size_t)64 * K + k0 + 32, lA + 2048);
      gload16(gb0 + k0 + 32, lB);
      gload16(gb0 + (size_t)64 * K + k0 + 32, lB + 2048);
    }
    bf16x8 a[4], b[4];
#pragma unroll
    for (int mi = 0; mi < 4; mi++)
      a[mi] = *(const bf16x8*)(As[cur] + (wy * 64 + mi * 16 + lr) * 32 + lg * 8);
#pragma unroll
    for (int ni = 0; ni < 4; ni++)
      b[ni] = *(const bf16x8*)(Bs[cur] + (wx * 64 + ni * 16 + lr) * 32 + lg * 8);
#pragma unroll
    for (int mi = 0; mi < 4; mi++)
#pragma unroll
      for (int ni = 0; ni < 4; ni++)
        acc[mi][ni] = __builtin_amdgcn_mfma_f32_16x16x32_bf16(a[mi], b[ni], acc[mi][ni], 0, 0, 0);
    __syncthreads();
    cur ^= 1;
  }
#pragma unroll
  for (int mi = 0; mi < 4; mi++)
#pragma unroll
    for (int ni = 0; ni < 4; ni++) {
      int col = n0 + wx * 64 + ni * 16 + lr;
      float bs = bias[col];
#pragma unroll
      for (int j = 0; j < 4; j++) {
        int row = m0 + wy * 64 + mi * 16 + lg * 4 + j;
        out[(size_t)row * D_ + col] = acc[mi][ni][j] + bs;
      }
    }
}

// ---------------- flash attention: swapped-operand 32x32, LDS-staged K/V ----------
// grid: 1024 blocks; bid = qt*64 + bh. 4 waves/block, each wave owns 32 q rows.
// KVBLK=64, double-buffered, prefetch 1 tile ahead, XOR-swizzle via pre-swizzled src.
// V fragments loaded AFTER softmax (time-share reg block with K frags).
__global__ __launch_bounds__(256, 2) void k_attn(
    const ushort_t* __restrict__ Qp, const ushort_t* __restrict__ Kp,
    const ushort_t* __restrict__ Vt, ushort_t* __restrict__ ctx) {
  __shared__ ushort_t Ks[2][64 * 64];   // [kv][dk] swizzled, 8KB each
  __shared__ ushort_t Vs[2][64 * 64];   // [d][t]  swizzled
  int bid = blockIdx.x;
  int bh = bid & 63;
  int qt = bid >> 6;
  int t = threadIdx.x;
  int l = t & 63, wid = t >> 6;
  int l31 = l & 31, hi = l >> 5;
  const float csc = 0.125f * 1.44269504f;  // scale * log2(e)

  const ushort_t* Qb = Qp + (size_t)bh * S_ * DK_;
  const ushort_t* Kb = Kp + (size_t)bh * S_ * DK_;
  const ushort_t* Vb = Vt + (size_t)bh * DK_ * S_;

  int q0 = qt * 128 + wid * 32;
  bf16x8 qf[4];
  const ushort_t* qp = Qb + (size_t)(q0 + l31) * DK_ + hi * 8;
#pragma unroll
  for (int ks = 0; ks < 4; ks++) qf[ks] = *(const bf16x8*)(qp + ks * 16);

  int sr0 = t >> 3;
  int sc0 = t & 7;
  int sr1 = sr0 + 32;
  const ushort_t* kg0 = Kb + (size_t)sr0 * DK_ + (sc0 ^ (sr0 & 7)) * 8;
  const ushort_t* kg1 = Kb + (size_t)sr1 * DK_ + (sc0 ^ (sr1 & 7)) * 8;
  const ushort_t* vg0 = Vb + (size_t)sr0 * S_ + (sc0 ^ (sr0 & 7)) * 8;
  const ushort_t* vg1 = Vb + (size_t)sr1 * S_ + (sc0 ^ (sr1 & 7)) * 8;

  f32x16 o0 = {}, o1 = {};
  float m = -1e30f, lsum = 0.f;

  {
    ushort_t* lK = Ks[0] + wid * 512;
    ushort_t* lV = Vs[0] + wid * 512;
    gload16(kg0, lK);
    gload16(kg1, lK + 2048);
    gload16(vg0, lV);
    gload16(vg1, lV + 2048);
  }
  __syncthreads();

  int cur = 0;
  for (int t0 = 0; t0 < S_; t0 += 64) {
    if (t0 + 64 < S_) {
      int nb = cur ^ 1;
      ushort_t* lK = Ks[nb] + wid * 512;
      ushort_t* lV = Vs[nb] + wid * 512;
      gload16(kg0 + (size_t)(t0 + 64) * DK_, lK);
      gload16(kg1 + (size_t)(t0 + 64) * DK_, lK + 2048);
      gload16(vg0 + t0 + 64, lV);
      gload16(vg1 + t0 + 64, lV + 2048);
    }

    // K fragments only (V loaded after softmax — time-share regs)
    int r0 = l31, r1 = l31 + 32;
    bf16x8 kf0[4], kf1[4];
    {
      const ushort_t* Kc = Ks[cur];
#pragma unroll
      for (int ks = 0; ks < 4; ks++) {
        int c = hi + 2 * ks;
        kf0[ks] = *(const bf16x8*)(Kc + r0 * 64 + ((c ^ (r0 & 7)) * 8));
        kf1[ks] = *(const bf16x8*)(Kc + r1 * 64 + ((c ^ (r1 & 7)) * 8));
      }
    }

    // S^T[kv][q] = K[kv][dk] * Q^T[dk][q]
    f32x16 s0 = {}, s1 = {};
#pragma unroll
    for (int ks = 0; ks < 4; ks++) {
      s0 = __builtin_amdgcn_mfma_f32_32x32x16_bf16(kf0[ks], qf[ks], s0, 0, 0, 0);
      s1 = __builtin_amdgcn_mfma_f32_32x32x16_bf16(kf1[ks], qf[ks], s1, 0, 0, 0);
    }

    // row max (lane owns q=l31; partner l^32 has other kv rows)
    float t0m = fmaxf(fmaxf(s0[0], s0[1]), s0[2]);
    float t1m = fmaxf(fmaxf(s0[3], s0[4]), s0[5]);
    float t2m = fmaxf(fmaxf(s0[6], s0[7]), s0[8]);
    float t3m = fmaxf(fmaxf(s0[9], s0[10]), s0[11]);
    float t4m = fmaxf(fmaxf(s0[12], s0[13]), s0[14]);
    float t5m = fmaxf(fmaxf(s0[15], s1[0]), s1[1]);
    float t6m = fmaxf(fmaxf(s1[2], s1[3]), s1[4]);
    float t7m = fmaxf(fmaxf(s1[5], s1[6]), s1[7]);
    float t8m = fmaxf(fmaxf(s1[8], s1[9]), s1[10]);
    float t9m = fmaxf(fmaxf(s1[11], s1[12]), s1[13]);
    float tam = fmaxf(s1[14], s1[15]);
    t0m = fmaxf(fmaxf(t0m, t1m), t2m);
    t3m = fmaxf(fmaxf(t3m, t4m), t5m);
    t6m = fmaxf(fmaxf(t6m, t7m), t8m);
    t9m = fmaxf(t9m, tam);
    float pmax = fmaxf(fmaxf(t0m, t3m), fmaxf(t6m, t9m));
    pmax = fmaxf(pmax, __shfl_xor(pmax, 32));
    pmax *= csc;

    // defer-max (T13)
    if (__any(pmax > m + 8.f)) {
      float mn = fmaxf(m, pmax);
      float a = exp2f(m - mn);
      m = mn;
      lsum *= a;
#pragma unroll
      for (int r = 0; r < 16; r++) { o0[r] *= a; o1[r] *= a; }
    }

    // P = exp2(S*csc - m); row sum
    float rs = 0.f;
#pragma unroll
    for (int r = 0; r < 16; r++) {
      s0[r] = exp2f(fmaf(s0[r], csc, -m));
      s1[r] = exp2f(fmaf(s1[r], csc, -m));
      rs += s0[r] + s1[r];
    }
    rs += __shfl_xor(rs, 32);
    lsum += rs;

    // P -> bf16 B-fragments (T12)
    union Frag { bf16x8 v; unsigned u[4]; } pb[4];
#pragma unroll
    for (int ct = 0; ct < 2; ct++) {
      const f32x16& p = (ct == 0) ? s0 : s1;
#pragma unroll
      for (int ksl = 0; ksl < 2; ksl++) {
        const int b = ksl * 8;
        unsigned a0, b0, a1, b1;
        asm("v_cvt_pk_bf16_f32 %0, %1, %2" : "=v"(a0) : "v"(p[b+0]), "v"(p[b+1]));
        asm("v_cvt_pk_bf16_f32 %0, %1, %2" : "=v"(b0) : "v"(p[b+4]), "v"(p[b+5]));
        asm("v_cvt_pk_bf16_f32 %0, %1, %2" : "=v"(a1) : "v"(p[b+2]), "v"(p[b+3]));
        asm("v_cvt_pk_bf16_f32 %0, %1, %2" : "=v"(b1) : "v"(p[b+6]), "v"(p[b+7]));
        plane32_swap(a0, b0);
        plane32_swap(a1, b1);
        Frag& f = pb[ct * 2 + ksl];
        f.u[0] = a0; f.u[1] = a1; f.u[2] = b0; f.u[3] = b1;
      }
    }

    // V fragments now (K frags dead)
    bf16x8 vf0[4], vf1[4];
    {
      const ushort_t* Vc = Vs[cur];
#pragma unroll
      for (int ks = 0; ks < 4; ks++) {
        int c = hi + 2 * ks;
        vf0[ks] = *(const bf16x8*)(Vc + r0 * 64 + ((c ^ (r0 & 7)) * 8));
        vf1[ks] = *(const bf16x8*)(Vc + r1 * 64 + ((c ^ (r1 & 7)) * 8));
      }
    }

    // O^T[d][q] += V^T[d][kv] * P^T[kv][q]
#pragma unroll
    for (int kvs = 0; kvs < 4; kvs++) {
      o0 = __builtin_amdgcn_mfma_f32_32x32x16_bf16(vf0[kvs], pb[kvs].v, o0, 0, 0, 0);
      o1 = __builtin_amdgcn_mfma_f32_32x32x16_bf16(vf1[kvs], pb[kvs].v, o1, 0, 0, 0);
    }

    __syncthreads();
    cur ^= 1;
  }

  // epilogue
  float inv = 1.f / lsum;
  int bb = bh >> 4, h = bh & 15;
  int srow = q0 + l31;
  ushort_t* cp = ctx + (((size_t)bb * S_ + srow) * H_ + h) * DK_;
#pragma unroll
  for (int dt = 0; dt < 2; dt++) {
    const f32x16& o = (dt == 0) ? o0 : o1;
#pragma unroll
    for (int g = 0; g < 4; g++) {
      ushort4 w;
      w.x = f2bf(o[4*g+0] * inv); w.y = f2bf(o[4*g+1] * inv);
      w.z = f2bf(o[4*g+2] * inv); w.w = f2bf(o[4*g+3] * inv);
      *(ushort4*)(cp + dt * 32 + 8 * g + 4 * hi) = w;
    }
  }
}

extern "C" void kernel_launch(void* const* d_in, const int* in_sizes, int n_in,
                              void* d_out, int out_size, void* d_ws, size_t ws_size,
                              hipStream_t stream) {
  const float* query = (const float*)d_in[0];
  const float* key   = (const float*)d_in[1];
  const float* value = (const float*)d_in[2];
  const float* Wq = (const float*)d_in[4];
  const float* bq = (const float*)d_in[5];
  const float* Wk = (const float*)d_in[6];
  const float* bk = (const float*)d_in[7];
  const float* Wv = (const float*)d_in[8];
  const float* bv = (const float*)d_in[9];
  const float* Wo = (const float*)d_in[10];
  const float* bo = (const float*)d_in[11];

  char* ws = (char*)d_ws;
  const size_t MD = (size_t)M_ * D_;      // 8388608 elements
  const size_t DD = (size_t)D_ * D_;
  ushort_t* xb  = (ushort_t*)ws;                              // [3][M][D] bf16 inputs
  ushort_t* wt  = (ushort_t*)(ws + 3 * MD * 2);               // [4][D][D] bf16 W^T
  ushort_t* Qp  = (ushort_t*)(ws + 3 * MD * 2 + 4 * DD * 2);  // [B,H,S,DK]
  ushort_t* Kp  = Qp + MD;
  ushort_t* Vt  = Kp + MD;   // [B,H,DK,S] (written transposed by fused GEMM)
  ushort_t* ctx = xb;        // reuse xb[0] (dead after fused QKV GEMM)

  k_convert<<<2048, 256, 0, stream>>>(query, key, value, xb);
  k_wtrans<<<1024, 256, 0, stream>>>(Wq, Wk, Wv, Wo, wt);
  k_gemm_qkv<<<1536, 256, 0, stream>>>(xb, wt, bq, bk, bv, Qp, Kp, Vt);
  k_attn<<<1024, 256, 0, stream>>>(Qp, Kp, Vt, ctx);
  k_gemm_o<<<512, 256, 0, stream>>>(ctx, wt + 3 * DD, bo, (float*)d_out);
}

// Round 6
// 372.152 us; speedup vs baseline: 1.5219x; 1.0587x over previous
//
#include <hip/hip_runtime.h>
#include <hip/hip_bf16.h>

#define B_ 4
#define S_ 2048
#define D_ 1024
#define H_ 16
#define DK_ 64
#define M_ (B_*S_)   // 8192

typedef unsigned short ushort_t;
typedef __bf16 bf16x8 __attribute__((ext_vector_type(8)));
typedef float f32x4 __attribute__((ext_vector_type(4)));
typedef float f32x16 __attribute__((ext_vector_type(16)));
typedef unsigned uint2v __attribute__((ext_vector_type(2)));

#define CSC (0.125f * 1.44269504f)   // attention scale * log2(e), folded into Q proj

__device__ __forceinline__ float fast_exp2(float x) {
#if __has_builtin(__builtin_amdgcn_exp2f)
  return __builtin_amdgcn_exp2f(x);
#else
  return exp2f(x);
#endif
}

__device__ __forceinline__ ushort_t f2bf(float f) {
  union { float f; unsigned u; } v; v.f = f;
  unsigned u = v.u;
  return (ushort_t)((u + 0x7fffu + ((u >> 16) & 1u)) >> 16);
}

__device__ __forceinline__ void gload16(const void* g, void* l) {
  __builtin_amdgcn_global_load_lds(
      (const __attribute__((address_space(1))) unsigned int*)g,
      (__attribute__((address_space(3))) unsigned int*)l, 16, 0, 0);
}

// swap(a.lane[i+32], b.lane[i]) — gfx950 v_permlane32_swap_b32
__device__ __forceinline__ void plane32_swap(unsigned& a, unsigned& b) {
#if __has_builtin(__builtin_amdgcn_permlane32_swap)
  uint2v r = __builtin_amdgcn_permlane32_swap(a, b, false, false);
  a = r.x; b = r.y;
#else
  unsigned pa = __shfl_xor((int)a, 32), pb = __shfl_xor((int)b, 32);
  bool hi = (threadIdx.x & 32) != 0;
  unsigned na = hi ? pb : a;
  unsigned nb = hi ? b : pa;
  a = na; b = nb;
#endif
}

// ---------------- convert q,k,v f32 -> bf16 ----------------
__global__ void k_convert(const float* __restrict__ q, const float* __restrict__ k,
                          const float* __restrict__ v, ushort_t* __restrict__ out) {
  const int n4 = (M_*D_) / 4;  // 2^21 per array
  int tid = blockIdx.x * blockDim.x + threadIdx.x;
  int stride = gridDim.x * blockDim.x;
  for (int i = tid; i < 3 * n4; i += stride) {
    int a = i >> 21;
    int r = i & (n4 - 1);
    const float4* src = (const float4*)(a == 0 ? q : (a == 1 ? k : v));
    float4 x = src[r];
    ushort4 o;
    o.x = f2bf(x.x); o.y = f2bf(x.y); o.z = f2bf(x.z); o.w = f2bf(x.w);
    *(ushort4*)(out + (size_t)a * (M_*D_) + (size_t)r * 4) = o;
  }
}

// ---------------- weight transpose+convert: Wt[n][k] = bf16(W[k][n]) ----------------
__global__ void k_wtrans(const float* __restrict__ Wq, const float* __restrict__ Wk,
                         const float* __restrict__ Wv, const float* __restrict__ Wo,
                         ushort_t* __restrict__ wt) {
  __shared__ ushort_t ls[64][72];
  int bid = blockIdx.x;
  int w = bid >> 8;
  int tile = bid & 255;
  int tk = (tile >> 4) * 64;
  int tn = (tile & 15) * 64;
  const float* W = (w == 0 ? Wq : w == 1 ? Wk : w == 2 ? Wv : Wo);
  int t = threadIdx.x;
  int r = t >> 4;
  int c = (t & 15) * 4;
#pragma unroll
  for (int i = 0; i < 4; i++) {
    int rr = r + i * 16;
    float4 x = *(const float4*)(W + (size_t)(tk + rr) * D_ + tn + c);
    ls[rr][c] = f2bf(x.x); ls[rr][c+1] = f2bf(x.y);
    ls[rr][c+2] = f2bf(x.z); ls[rr][c+3] = f2bf(x.w);
  }
  __syncthreads();
  ushort_t* dst = wt + (size_t)w * D_ * D_;
#pragma unroll
  for (int i = 0; i < 4; i++) {
    int rr = r + i * 16;
    ushort4 o;
    o.x = ls[c+0][rr]; o.y = ls[c+1][rr]; o.z = ls[c+2][rr]; o.w = ls[c+3][rr];
    *(ushort4*)(dst + (size_t)(tn + rr) * D_ + tk + c) = o;
  }
}

// ---------------- fused QKV GEMM: N=3072, per-block A selected by col-block -----
// col block w = 0/1/2 -> A = xq/xk/xv, Bt = Wt_w, bias = bq/bk/bv.
// Q out: pre-scaled by CSC. Q,K out: [B,H,S,DK] bf16. V out: transposed Vt[bh][d][s].
__global__ __launch_bounds__(256, 2) void k_gemm_qkv(
    const ushort_t* __restrict__ X, const ushort_t* __restrict__ Wt,
    const float* __restrict__ bq, const float* __restrict__ bk,
    const float* __restrict__ bv,
    ushort_t* __restrict__ Qp, ushort_t* __restrict__ Kp,
    ushort_t* __restrict__ VtT) {
  __shared__ ushort_t As[2][128 * 32];
  __shared__ ushort_t Bs[2][128 * 32];
  const int K = D_;
  const size_t MD = (size_t)M_ * D_;
  const size_t DD = (size_t)D_ * D_;
  int nwg = gridDim.x;           // 1536, divisible by 8
  int cpx = nwg >> 3;            // 192
  int bid = blockIdx.x;
  int wg = (bid & 7) * cpx + (bid >> 3);   // XCD-aware swizzle (bijective)
  int by = wg / 24;              // 0..63  (row tile)
  int bx = wg % 24;              // 0..23  (col tile)
  int w = bx >> 3;               // which projection
  int m0 = by * 128, n0 = (bx & 7) * 128;
  int t = threadIdx.x;
  int l = t & 63, wid = t >> 6;
  int wy = wid >> 1, wx = wid & 1;
  int lr = l & 15, lg = l >> 4;

  const ushort_t* A  = X  + (size_t)w * MD;
  const ushort_t* Bt = Wt + (size_t)w * DD;

  f32x4 acc[4][4] = {};
  const ushort_t* ga0 = A  + (size_t)(m0 + (t >> 2)) * K + (t & 3) * 8;
  const ushort_t* gb0 = Bt + (size_t)(n0 + (t >> 2)) * K + (t & 3) * 8;

  {
    ushort_t* lA = As[0] + wid * 512;
    ushort_t* lB = Bs[0] + wid * 512;
    gload16(ga0, lA);
    gload16(ga0 + (size_t)64 * K, lA + 2048);
    gload16(gb0, lB);
    gload16(gb0 + (size_t)64 * K, lB + 2048);
  }
  __syncthreads();

  int cur = 0;
  for (int k0 = 0; k0 < K; k0 += 32) {
    if (k0 + 32 < K) {
      int nb = cur ^ 1;
      ushort_t* lA = As[nb] + wid * 512;
      ushort_t* lB = Bs[nb] + wid * 512;
      gload16(ga0 + k0 + 32, lA);
      gload16(ga0 + (size_t)64 * K + k0 + 32, lA + 2048);
      gload16(gb0 + k0 + 32, lB);
      gload16(gb0 + (size_t)64 * K + k0 + 32, lB + 2048);
    }
    bf16x8 a[4], b[4];
#pragma unroll
    for (int mi = 0; mi < 4; mi++)
      a[mi] = *(const bf16x8*)(As[cur] + (wy * 64 + mi * 16 + lr) * 32 + lg * 8);
#pragma unroll
    for (int ni = 0; ni < 4; ni++)
      b[ni] = *(const bf16x8*)(Bs[cur] + (wx * 64 + ni * 16 + lr) * 32 + lg * 8);
#pragma unroll
    for (int mi = 0; mi < 4; mi++)
#pragma unroll
      for (int ni = 0; ni < 4; ni++)
        acc[mi][ni] = __builtin_amdgcn_mfma_f32_16x16x32_bf16(a[mi], b[ni], acc[mi][ni], 0, 0, 0);
    __syncthreads();
    cur ^= 1;
  }

  const float* bp = (w == 0 ? bq : w == 1 ? bk : bv);
#pragma unroll
  for (int mi = 0; mi < 4; mi++)
#pragma unroll
    for (int ni = 0; ni < 4; ni++) {
      int cl = n0 + wx * 64 + ni * 16 + lr;   // 0..1023
      float bs = bp[cl];
      int h = cl >> 6, d = cl & 63;
      int row0 = m0 + wy * 64 + mi * 16 + lg * 4;
      int bi = row0 >> 11, s0 = row0 & 2047;
      if (w == 2) {
        ushort4 o;
        o.x = f2bf(acc[mi][ni][0] + bs); o.y = f2bf(acc[mi][ni][1] + bs);
        o.z = f2bf(acc[mi][ni][2] + bs); o.w = f2bf(acc[mi][ni][3] + bs);
        *(ushort4*)(VtT + (((size_t)bi * H_ + h) * DK_ + d) * S_ + s0) = o;
      } else if (w == 0) {
        // Q: fold softmax scale (CSC) in here — frees VALU in k_attn's hot loop
#pragma unroll
        for (int j = 0; j < 4; j++) {
          float val = (acc[mi][ni][j] + bs) * CSC;
          Qp[(((size_t)bi * H_ + h) * S_ + (s0 + j)) * DK_ + d] = f2bf(val);
        }
      } else {
#pragma unroll
        for (int j = 0; j < 4; j++) {
          float val = acc[mi][ni][j] + bs;
          Kp[(((size_t)bi * H_ + h) * S_ + (s0 + j)) * DK_ + d] = f2bf(val);
        }
      }
    }
}

// ---------------- final GEMM: C[M,1024] = ctx @ Wo^T + bo, f32 out ---------------
__global__ __launch_bounds__(256, 2) void k_gemm_o(
    const ushort_t* __restrict__ A, const ushort_t* __restrict__ Bt,
    const float* __restrict__ bias, float* __restrict__ out) {
  __shared__ ushort_t As[2][128 * 32];
  __shared__ ushort_t Bs[2][128 * 32];
  const int K = D_;
  int nwg = gridDim.x;           // 512
  int cpx = nwg >> 3;
  int bid = blockIdx.x;
  int wg = (bid & 7) * cpx + (bid >> 3);
  int by = wg >> 3;
  int bx = wg & 7;
  int m0 = by * 128, n0 = bx * 128;
  int t = threadIdx.x;
  int l = t & 63, wid = t >> 6;
  int wy = wid >> 1, wx = wid & 1;
  int lr = l & 15, lg = l >> 4;

  f32x4 acc[4][4] = {};
  const ushort_t* ga0 = A  + (size_t)(m0 + (t >> 2)) * K + (t & 3) * 8;
  const ushort_t* gb0 = Bt + (size_t)(n0 + (t >> 2)) * K + (t & 3) * 8;

  {
    ushort_t* lA = As[0] + wid * 512;
    ushort_t* lB = Bs[0] + wid * 512;
    gload16(ga0, lA);
    gload16(ga0 + (size_t)64 * K, lA + 2048);
    gload16(gb0, lB);
    gload16(gb0 + (size_t)64 * K, lB + 2048);
  }
  __syncthreads();

  int cur = 0;
  for (int k0 = 0; k0 < K; k0 += 32) {
    if (k0 + 32 < K) {
      int nb = cur ^ 1;
      ushort_t* lA = As[nb] + wid * 512;
      ushort_t* lB = Bs[nb] + wid * 512;
      gload16(ga0 + k0 + 32, lA);
      gload16(ga0 + (size_t)64 * K + k0 + 32, lA + 2048);
      gload16(gb0 + k0 + 32, lB);
      gload16(gb0 + (size_t)64 * K + k0 + 32, lB + 2048);
    }
    bf16x8 a[4], b[4];
#pragma unroll
    for (int mi = 0; mi < 4; mi++)
      a[mi] = *(const bf16x8*)(As[cur] + (wy * 64 + mi * 16 + lr) * 32 + lg * 8);
#pragma unroll
    for (int ni = 0; ni < 4; ni++)
      b[ni] = *(const bf16x8*)(Bs[cur] + (wx * 64 + ni * 16 + lr) * 32 + lg * 8);
#pragma unroll
    for (int mi = 0; mi < 4; mi++)
#pragma unroll
      for (int ni = 0; ni < 4; ni++)
        acc[mi][ni] = __builtin_amdgcn_mfma_f32_16x16x32_bf16(a[mi], b[ni], acc[mi][ni], 0, 0, 0);
    __syncthreads();
    cur ^= 1;
  }
#pragma unroll
  for (int mi = 0; mi < 4; mi++)
#pragma unroll
    for (int ni = 0; ni < 4; ni++) {
      int col = n0 + wx * 64 + ni * 16 + lr;
      float bs = bias[col];
#pragma unroll
      for (int j = 0; j < 4; j++) {
        int row = m0 + wy * 64 + mi * 16 + lg * 4 + j;
        out[(size_t)row * D_ + col] = acc[mi][ni][j] + bs;
      }
    }
}

// ---------------- flash attention: swapped-operand 32x32, LDS-staged K/V ----------
// grid: 1024 blocks; bid = qt*64 + bh. 4 waves/block, 32 q rows/wave, KVBLK=64.
// Double-buffered, prefetch 1 tile ahead, XOR-swizzle via pre-swizzled global src.
// s0/s1 forced to VGPRs after QK^T (AGPR softmax-move elimination).
__global__ __launch_bounds__(256, 3) void k_attn(
    const ushort_t* __restrict__ Qp, const ushort_t* __restrict__ Kp,
    const ushort_t* __restrict__ Vt, ushort_t* __restrict__ ctx) {
  __shared__ ushort_t Ks[2][64 * 64];   // [kv][dk] swizzled, 8KB each
  __shared__ ushort_t Vs[2][64 * 64];   // [d][t]  swizzled
  int bid = blockIdx.x;
  int bh = bid & 63;
  int qt = bid >> 6;
  int t = threadIdx.x;
  int l = t & 63, wid = t >> 6;
  int l31 = l & 31, hi = l >> 5;

  const ushort_t* Qb = Qp + (size_t)bh * S_ * DK_;
  const ushort_t* Kb = Kp + (size_t)bh * S_ * DK_;
  const ushort_t* Vb = Vt + (size_t)bh * DK_ * S_;

  int q0 = qt * 128 + wid * 32;
  bf16x8 qf[4];
  const ushort_t* qp = Qb + (size_t)(q0 + l31) * DK_ + hi * 8;
#pragma unroll
  for (int ks = 0; ks < 4; ks++) qf[ks] = *(const bf16x8*)(qp + ks * 16);

  int sr0 = t >> 3;
  int sc0 = t & 7;
  int sr1 = sr0 + 32;
  const ushort_t* kg0 = Kb + (size_t)sr0 * DK_ + (sc0 ^ (sr0 & 7)) * 8;
  const ushort_t* kg1 = Kb + (size_t)sr1 * DK_ + (sc0 ^ (sr1 & 7)) * 8;
  const ushort_t* vg0 = Vb + (size_t)sr0 * S_ + (sc0 ^ (sr0 & 7)) * 8;
  const ushort_t* vg1 = Vb + (size_t)sr1 * S_ + (sc0 ^ (sr1 & 7)) * 8;

  f32x16 o0 = {}, o1 = {};
  float m = -1e30f, lsum = 0.f;   // lsum is per-lane partial (32 kv); combined at end

  {
    ushort_t* lK = Ks[0] + wid * 512;
    ushort_t* lV = Vs[0] + wid * 512;
    gload16(kg0, lK);
    gload16(kg1, lK + 2048);
    gload16(vg0, lV);
    gload16(vg1, lV + 2048);
  }
  __syncthreads();

  int cur = 0;
  for (int t0 = 0; t0 < S_; t0 += 64) {
    if (t0 + 64 < S_) {
      int nb = cur ^ 1;
      ushort_t* lK = Ks[nb] + wid * 512;
      ushort_t* lV = Vs[nb] + wid * 512;
      gload16(kg0 + (size_t)(t0 + 64) * DK_, lK);
      gload16(kg1 + (size_t)(t0 + 64) * DK_, lK + 2048);
      gload16(vg0 + t0 + 64, lV);
      gload16(vg1 + t0 + 64, lV + 2048);
    }

    // K fragments (V later — time-share regs)
    int r0 = l31, r1 = l31 + 32;
    bf16x8 kf0[4], kf1[4];
    {
      const ushort_t* Kc = Ks[cur];
#pragma unroll
      for (int ks = 0; ks < 4; ks++) {
        int c = hi + 2 * ks;
        kf0[ks] = *(const bf16x8*)(Kc + r0 * 64 + ((c ^ (r0 & 7)) * 8));
        kf1[ks] = *(const bf16x8*)(Kc + r1 * 64 + ((c ^ (r1 & 7)) * 8));
      }
    }

    // S^T[kv][q] = K[kv][dk] * Q^T[dk][q]  (Q pre-scaled by CSC)
    f32x16 s0 = {}, s1 = {};
#pragma unroll
    for (int ks = 0; ks < 4; ks++) {
      s0 = __builtin_amdgcn_mfma_f32_32x32x16_bf16(kf0[ks], qf[ks], s0, 0, 0, 0);
      s1 = __builtin_amdgcn_mfma_f32_32x32x16_bf16(kf1[ks], qf[ks], s1, 0, 0, 0);
    }

    // force scores into VGPRs (compiler places MFMA acc in AGPRs; softmax on
    // AGPR-resident values inflates VALU via accvgpr moves — one bulk move here)
#pragma unroll
    for (int r = 0; r < 16; r++) {
      asm("" : "+v"(s0[r]));
      asm("" : "+v"(s1[r]));
    }

    // row max (lane owns q=l31; partner l^32 has other kv rows)
    float t0m = fmaxf(fmaxf(s0[0], s0[1]), s0[2]);
    float t1m = fmaxf(fmaxf(s0[3], s0[4]), s0[5]);
    float t2m = fmaxf(fmaxf(s0[6], s0[7]), s0[8]);
    float t3m = fmaxf(fmaxf(s0[9], s0[10]), s0[11]);
    float t4m = fmaxf(fmaxf(s0[12], s0[13]), s0[14]);
    float t5m = fmaxf(fmaxf(s0[15], s1[0]), s1[1]);
    float t6m = fmaxf(fmaxf(s1[2], s1[3]), s1[4]);
    float t7m = fmaxf(fmaxf(s1[5], s1[6]), s1[7]);
    float t8m = fmaxf(fmaxf(s1[8], s1[9]), s1[10]);
    float t9m = fmaxf(fmaxf(s1[11], s1[12]), s1[13]);
    float tam = fmaxf(s1[14], s1[15]);
    t0m = fmaxf(fmaxf(t0m, t1m), t2m);
    t3m = fmaxf(fmaxf(t3m, t4m), t5m);
    t6m = fmaxf(fmaxf(t6m, t7m), t8m);
    t9m = fmaxf(t9m, tam);
    float pmax = fmaxf(fmaxf(t0m, t3m), fmaxf(t6m, t9m));
    pmax = fmaxf(pmax, __shfl_xor(pmax, 32));

    // defer-max (T13)
    if (__any(pmax > m + 8.f)) {
      float mn = fmaxf(m, pmax);
      float a = fast_exp2(m - mn);
      m = mn;
      lsum *= a;
#pragma unroll
      for (int r = 0; r < 16; r++) { o0[r] *= a; o1[r] *= a; }
    }

    // P = exp2(S - m); per-lane partial row sum
    float rs = 0.f;
#pragma unroll
    for (int r = 0; r < 16; r++) {
      s0[r] = fast_exp2(s0[r] - m);
      s1[r] = fast_exp2(s1[r] - m);
      rs += s0[r] + s1[r];
    }
    lsum += rs;

    // P -> bf16 B-fragments (T12)
    union Frag { bf16x8 v; unsigned u[4]; } pb[4];
#pragma unroll
    for (int ct = 0; ct < 2; ct++) {
      const f32x16& p = (ct == 0) ? s0 : s1;
#pragma unroll
      for (int ksl = 0; ksl < 2; ksl++) {
        const int b = ksl * 8;
        unsigned a0, b0, a1, b1;
        asm("v_cvt_pk_bf16_f32 %0, %1, %2" : "=v"(a0) : "v"(p[b+0]), "v"(p[b+1]));
        asm("v_cvt_pk_bf16_f32 %0, %1, %2" : "=v"(b0) : "v"(p[b+4]), "v"(p[b+5]));
        asm("v_cvt_pk_bf16_f32 %0, %1, %2" : "=v"(a1) : "v"(p[b+2]), "v"(p[b+3]));
        asm("v_cvt_pk_bf16_f32 %0, %1, %2" : "=v"(b1) : "v"(p[b+6]), "v"(p[b+7]));
        plane32_swap(a0, b0);
        plane32_swap(a1, b1);
        Frag& f = pb[ct * 2 + ksl];
        f.u[0] = a0; f.u[1] = a1; f.u[2] = b0; f.u[3] = b1;
      }
    }

    // V fragments (K frags dead)
    bf16x8 vf0[4], vf1[4];
    {
      const ushort_t* Vc = Vs[cur];
#pragma unroll
      for (int ks = 0; ks < 4; ks++) {
        int c = hi + 2 * ks;
        vf0[ks] = *(const bf16x8*)(Vc + r0 * 64 + ((c ^ (r0 & 7)) * 8));
        vf1[ks] = *(const bf16x8*)(Vc + r1 * 64 + ((c ^ (r1 & 7)) * 8));
      }
    }

    // O^T[d][q] += V^T[d][kv] * P^T[kv][q]
#pragma unroll
    for (int kvs = 0; kvs < 4; kvs++) {
      o0 = __builtin_amdgcn_mfma_f32_32x32x16_bf16(vf0[kvs], pb[kvs].v, o0, 0, 0, 0);
      o1 = __builtin_amdgcn_mfma_f32_32x32x16_bf16(vf1[kvs], pb[kvs].v, o1, 0, 0, 0);
    }

    __syncthreads();
    cur ^= 1;
  }

  // epilogue: combine lane-pair partial sums, normalize, store
  float ltot = lsum + __shfl_xor(lsum, 32);
  float inv = 1.f / ltot;
  int bb = bh >> 4, h = bh & 15;
  int srow = q0 + l31;
  ushort_t* cp = ctx + (((size_t)bb * S_ + srow) * H_ + h) * DK_;
#pragma unroll
  for (int dt = 0; dt < 2; dt++) {
    const f32x16& o = (dt == 0) ? o0 : o1;
#pragma unroll
    for (int g = 0; g < 4; g++) {
      ushort4 w;
      w.x = f2bf(o[4*g+0] * inv); w.y = f2bf(o[4*g+1] * inv);
      w.z = f2bf(o[4*g+2] * inv); w.w = f2bf(o[4*g+3] * inv);
      *(ushort4*)(cp + dt * 32 + 8 * g + 4 * hi) = w;
    }
  }
}

extern "C" void kernel_launch(void* const* d_in, const int* in_sizes, int n_in,
                              void* d_out, int out_size, void* d_ws, size_t ws_size,
                              hipStream_t stream) {
  const float* query = (const float*)d_in[0];
  const float* key   = (const float*)d_in[1];
  const float* value = (const float*)d_in[2];
  const float* Wq = (const float*)d_in[4];
  const float* bq = (const float*)d_in[5];
  const float* Wk = (const float*)d_in[6];
  const float* bk = (const float*)d_in[7];
  const float* Wv = (const float*)d_in[8];
  const float* bv = (const float*)d_in[9];
  const float* Wo = (const float*)d_in[10];
  const float* bo = (const float*)d_in[11];

  char* ws = (char*)d_ws;
  const size_t MD = (size_t)M_ * D_;      // 8388608 elements
  const size_t DD = (size_t)D_ * D_;
  ushort_t* xb  = (ushort_t*)ws;                              // [3][M][D] bf16 inputs
  ushort_t* wt  = (ushort_t*)(ws + 3 * MD * 2);               // [4][D][D] bf16 W^T
  ushort_t* Qp  = (ushort_t*)(ws + 3 * MD * 2 + 4 * DD * 2);  // [B,H,S,DK]
  ushort_t* Kp  = Qp + MD;
  ushort_t* Vt  = Kp + MD;   // [B,H,DK,S] (written transposed by fused GEMM)
  ushort_t* ctx = xb;        // reuse xb[0] (dead after fused QKV GEMM)

  k_convert<<<2048, 256, 0, stream>>>(query, key, value, xb);
  k_wtrans<<<1024, 256, 0, stream>>>(Wq, Wk, Wv, Wo, wt);
  k_gemm_qkv<<<1536, 256, 0, stream>>>(xb, wt, bq, bk, bv, Qp, Kp, Vt);
  k_attn<<<1024, 256, 0, stream>>>(Qp, Kp, Vt, ctx);
  k_gemm_o<<<512, 256, 0, stream>>>(ctx, wt + 3 * DD, bo, (float*)d_out);
}